// Round 2
// baseline (1227.099 us; speedup 1.0000x reference)
//
#include <hip/hip_runtime.h>

// ---------------------------------------------------------------------------
// GIN GraphEncoder on MI355X.
// Pipeline per layer: h = x + CSR-gather-sum(x)  ->  z = h@Wa + ba (MFMA,
// split-bf16 hi/lo 3-product for ~f32 accuracy) -> BN stats -> fold scale/shift
// -> out = relu_bn(z)@Wb + bb (+tanh/relu epilogue).
// Then graph mean-pool (sorted batch -> boundaries) + 2 small f32 head GEMMs.
// NOTE: harness delivers integer inputs as int32 (NOT the reference's int64).
// ---------------------------------------------------------------------------

typedef __attribute__((ext_vector_type(8))) short short8;   // 8 bf16 for MFMA
typedef __attribute__((ext_vector_type(4))) float f32x4;
typedef __attribute__((ext_vector_type(4))) unsigned short us4;
typedef __attribute__((ext_vector_type(8))) unsigned short us8;

__device__ __forceinline__ unsigned short f2bf(float f) {
  unsigned int b = __float_as_uint(f);
  unsigned int r = 0x7FFFu + ((b >> 16) & 1u);   // round-to-nearest-even
  return (unsigned short)((b + r) >> 16);
}
__device__ __forceinline__ float bf2f(unsigned short u) {
  return __uint_as_float(((unsigned int)u) << 16);
}

// ---------------- CSR build ----------------
__global__ void k_hist(const int* __restrict__ ei, int* __restrict__ deg, int E) {
  int e = blockIdx.x * 256 + threadIdx.x;
  if (e >= E) return;
  atomicAdd(&deg[ei[E + e]], 1);
}

__global__ __launch_bounds__(1024) void k_scan(const int* __restrict__ deg,
                                               int* __restrict__ rowptr,
                                               int* __restrict__ cursor, int N) {
  __shared__ int sd[1024];
  __shared__ int running;
  int tid = threadIdx.x;
  if (tid == 0) { running = 0; rowptr[0] = 0; }
  __syncthreads();
  int iters = (N + 1023) >> 10;
  for (int it = 0; it < iters; ++it) {
    int i = (it << 10) + tid;
    int v = (i < N) ? deg[i] : 0;
    sd[tid] = v;
    __syncthreads();
    for (int off = 1; off < 1024; off <<= 1) {
      int t = (tid >= off) ? sd[tid - off] : 0;
      __syncthreads();
      sd[tid] += t;
      __syncthreads();
    }
    int roff = running;
    int incl = sd[tid] + roff;
    if (i < N) { rowptr[i + 1] = incl; cursor[i] = incl - v; }
    __syncthreads();
    if (tid == 1023) running = incl;
    __syncthreads();
  }
}

__global__ void k_fill(const int* __restrict__ ei, int* __restrict__ cursor,
                       int* __restrict__ adj, int E) {
  int e = blockIdx.x * 256 + threadIdx.x;
  if (e >= E) return;
  int s = ei[e];
  int d = ei[E + e];
  int pos = atomicAdd(&cursor[d], 1);
  adj[pos] = s;
}

// ---------------- weight transpose + bf16 hi/lo split: W[K][256] -> Wt[256][K]
__global__ void k_prep(const float* __restrict__ W, unsigned short* __restrict__ Hi,
                       unsigned short* __restrict__ Lo, int K) {
  int idx = blockIdx.x * 256 + threadIdx.x;
  int n = idx & 255, k = idx >> 8;
  if (k >= K) return;
  float w = W[k * 256 + n];
  unsigned short h = f2bf(w);
  Hi[n * K + k] = h;
  Lo[n * K + k] = f2bf(w - bf2f(h));
}

// ---------------- aggregation: H[i] = X[i] + sum_{e in CSR(i)} X[adj[e]] ----
template <int C>
__global__ __launch_bounds__(256) void k_agg(const float* __restrict__ X,
                                             float* __restrict__ H,
                                             const int* __restrict__ rowptr,
                                             const int* __restrict__ adj, int N) {
  int node = blockIdx.x * 4 + (threadIdx.x >> 6);
  if (node >= N) return;
  int lane = threadIdx.x & 63;
  int e0 = rowptr[node], e1 = rowptr[node + 1];
  if constexpr (C == 256) {
    float4 acc = ((const float4*)(X + (size_t)node * C))[lane];
    for (int e = e0; e < e1; ++e) {
      int s = adj[e];
      float4 v = ((const float4*)(X + (size_t)s * C))[lane];
      acc.x += v.x; acc.y += v.y; acc.z += v.z; acc.w += v.w;
    }
    ((float4*)(H + (size_t)node * C))[lane] = acc;
  } else {  // C == 128
    float2 acc = ((const float2*)(X + (size_t)node * C))[lane];
    for (int e = e0; e < e1; ++e) {
      int s = adj[e];
      float2 v = ((const float2*)(X + (size_t)s * C))[lane];
      acc.x += v.x; acc.y += v.y;
    }
    ((float2*)(H + (size_t)node * C))[lane] = acc;
  }
}

// ---------------- MFMA GEMM: Out[M][256] = f(A[M][K]) @ W[K][256] + bias ----
// Split-bf16: A = aHi + aLo, W = wHi + wLo; acc += aHi*wHi + aHi*wLo + aLo*wHi.
// BNP: A-load prologue relu(a*scale+shift).  EPI: 0 none, 1 relu, 2 tanh, 3 relu(tanh).
template <bool BNP, int EPI>
__global__ __launch_bounds__(256) void k_gemm(const float* __restrict__ A, int M, int K,
                                              const unsigned short* __restrict__ WHi,
                                              const unsigned short* __restrict__ WLo,
                                              const float* __restrict__ bias,
                                              const float* __restrict__ scsh,
                                              float* __restrict__ Out) {
  __shared__ unsigned short aHi[128][56], aLo[128][56];  // pad 32->56: 16B-aligned rows
  __shared__ unsigned short bHi[128][56], bLo[128][56];
  const int tid = threadIdx.x;
  const int lane = tid & 63, w = tid >> 6;
  const int wm = w >> 1, wn = w & 1;
  const int m0 = blockIdx.x * 128;
  const int n0 = blockIdx.y * 128;

  f32x4 zero = {0.f, 0.f, 0.f, 0.f};
  f32x4 acc[4][4];
#pragma unroll
  for (int i = 0; i < 4; ++i)
#pragma unroll
    for (int j = 0; j < 4; ++j) acc[i][j] = zero;

  for (int kb = 0; kb < K; kb += 32) {
    __syncthreads();
    // stage A tile 128x32 f32 -> bf16 hi/lo (with optional BN+relu prologue)
#pragma unroll
    for (int q = 0; q < 4; ++q) {
      int idx = tid + q * 256;          // float4 index, 1024 total
      int row = idx >> 3, kq = idx & 7;
      int grow = m0 + row;
      float vv[4] = {0.f, 0.f, 0.f, 0.f};
      if (grow < M) {
        const float4 v = *(const float4*)(A + (size_t)grow * K + kb + kq * 4);
        vv[0] = v.x; vv[1] = v.y; vv[2] = v.z; vv[3] = v.w;
      }
      us4 hv, lv;
#pragma unroll
      for (int j = 0; j < 4; ++j) {
        float f = vv[j];
        if (BNP) {
          int kc = kb + kq * 4 + j;
          f = fmaxf(f * scsh[kc] + scsh[256 + kc], 0.f);
        }
        unsigned short h = f2bf(f);
        hv[j] = h;
        lv[j] = f2bf(f - bf2f(h));
      }
      *(us4*)&aHi[row][kq * 4] = hv;
      *(us4*)&aLo[row][kq * 4] = lv;
    }
    // stage B tile: Wt rows [n0, n0+128) x 32 k, pre-split bf16
#pragma unroll
    for (int q = 0; q < 2; ++q) {
      int idx = tid + q * 256;          // 8-elem chunk index, 512 total
      int nrow = idx >> 2, k8 = idx & 3;
      size_t go = (size_t)(n0 + nrow) * K + kb + k8 * 8;
      *(us8*)&bHi[nrow][k8 * 8] = *(const us8*)(WHi + go);
      *(us8*)&bLo[nrow][k8 * 8] = *(const us8*)(WLo + go);
    }
    __syncthreads();

    const int ko = (lane >> 4) * 8;
    short8 bh[4], bl[4];
#pragma unroll
    for (int ni = 0; ni < 4; ++ni) {
      int r = wn * 64 + ni * 16 + (lane & 15);
      bh[ni] = *(const short8*)&bHi[r][ko];
      bl[ni] = *(const short8*)&bLo[r][ko];
    }
#pragma unroll
    for (int mi = 0; mi < 4; ++mi) {
      int r = wm * 64 + mi * 16 + (lane & 15);
      short8 ah = *(const short8*)&aHi[r][ko];
      short8 al = *(const short8*)&aLo[r][ko];
#pragma unroll
      for (int ni = 0; ni < 4; ++ni) {
        acc[mi][ni] = __builtin_amdgcn_mfma_f32_16x16x32_bf16(ah, bh[ni], acc[mi][ni], 0, 0, 0);
        acc[mi][ni] = __builtin_amdgcn_mfma_f32_16x16x32_bf16(ah, bl[ni], acc[mi][ni], 0, 0, 0);
        acc[mi][ni] = __builtin_amdgcn_mfma_f32_16x16x32_bf16(al, bh[ni], acc[mi][ni], 0, 0, 0);
      }
    }
  }

  // epilogue: C/D layout col = lane&15, row = (lane>>4)*4 + r   [m89-verified]
#pragma unroll
  for (int mi = 0; mi < 4; ++mi) {
    int rbase = m0 + wm * 64 + mi * 16 + (lane >> 4) * 4;
#pragma unroll
    for (int ni = 0; ni < 4; ++ni) {
      int col = n0 + wn * 64 + ni * 16 + (lane & 15);
      float bc = bias[col];
#pragma unroll
      for (int r = 0; r < 4; ++r) {
        int row = rbase + r;
        if (row < M) {
          float o = acc[mi][ni][r] + bc;
          if (EPI == 1) o = fmaxf(o, 0.f);
          else if (EPI == 2) o = tanhf(o);
          else if (EPI == 3) o = fmaxf(tanhf(o), 0.f);
          Out[(size_t)row * 256 + col] = o;
        }
      }
    }
  }
}

// ---------------- BN stats ----------------
__global__ __launch_bounds__(256) void k_stats(const float* __restrict__ Z,
                                               float* __restrict__ stats, int M) {
  int col = threadIdx.x;
  int rowsPer = (M + gridDim.x - 1) / gridDim.x;
  int r0 = blockIdx.x * rowsPer;
  int r1 = min(M, r0 + rowsPer);
  float s = 0.f, q = 0.f;
  for (int r = r0; r < r1; ++r) {
    float v = Z[(size_t)r * 256 + col];
    s += v;
    q += v * v;
  }
  atomicAdd(&stats[col], s);
  atomicAdd(&stats[256 + col], q);
}

__global__ void k_finalize(const float* __restrict__ stats, const float* __restrict__ g,
                           const float* __restrict__ be, float* __restrict__ scsh, int M) {
  int c = threadIdx.x;
  float mu = stats[c] / (float)M;
  float var = stats[256 + c] / (float)M - mu * mu;
  float sc = g[c] * rsqrtf(var + 1e-5f);
  scsh[c] = sc;
  scsh[256 + c] = be[c] - mu * sc;
}

// ---------------- pooling ----------------
__global__ void k_bounds(const int* __restrict__ batch, int* __restrict__ gs,
                         int* __restrict__ ge, int N) {
  int i = blockIdx.x * 256 + threadIdx.x;
  if (i >= N) return;
  int b = batch[i];
  if (i == 0 || batch[i - 1] != b) gs[b] = i;
  if (i == N - 1 || batch[i + 1] != b) ge[b] = i + 1;
}

__global__ __launch_bounds__(256) void k_pool(const float* __restrict__ Hf,
                                              const int* __restrict__ gs,
                                              const int* __restrict__ ge,
                                              float* __restrict__ pooled) {
  int g = blockIdx.x;
  int s = gs[g], e = ge[g];
  float acc = 0.f;
  for (int r = s; r < e; ++r) acc += Hf[(size_t)r * 256 + threadIdx.x];
  pooled[g * 256 + threadIdx.x] = acc / fmaxf((float)(e - s), 1.0f);
}

// ---------------- f32 head GEMMs (tiny) ----------------
__global__ __launch_bounds__(256) void k_head1(const float* __restrict__ P,
                                               const float* __restrict__ W,
                                               const float* __restrict__ b,
                                               float* __restrict__ T) {
  __shared__ float arow[256];
  int m = blockIdx.x;
  arow[threadIdx.x] = P[m * 256 + threadIdx.x];
  __syncthreads();
#pragma unroll
  for (int nn = 0; nn < 2; ++nn) {
    int n = threadIdx.x + nn * 256;
    float acc = b[n];
#pragma unroll 4
    for (int k = 0; k < 256; ++k) acc += arow[k] * W[k * 512 + n];
    T[m * 512 + n] = fmaxf(acc, 0.f);
  }
}

__global__ __launch_bounds__(256) void k_head2(const float* __restrict__ T,
                                               const float* __restrict__ W,
                                               const float* __restrict__ b,
                                               float* __restrict__ Out) {
  __shared__ float arow[512];
  int m = blockIdx.x;
  arow[threadIdx.x] = T[m * 512 + threadIdx.x];
  arow[256 + threadIdx.x] = T[m * 512 + 256 + threadIdx.x];
  __syncthreads();
#pragma unroll
  for (int nn = 0; nn < 3; ++nn) {
    int n = threadIdx.x + nn * 256;
    float acc = b[n];
#pragma unroll 4
    for (int k = 0; k < 512; ++k) acc += arow[k] * W[k * 768 + n];
    Out[m * 768 + n] = acc;
  }
}

// ---------------------------------------------------------------------------
extern "C" void kernel_launch(void* const* d_in, const int* in_sizes, int n_in,
                              void* d_out, int out_size, void* d_ws, size_t ws_size,
                              hipStream_t stream) {
  const float* x      = (const float*)d_in[0];
  const int* ei       = (const int*)d_in[1];    // harness delivers int32
  const int* bat      = (const int*)d_in[2];    // harness delivers int32
  const float* w1a = (const float*)d_in[3];  const float* b1a = (const float*)d_in[4];
  const float* g1  = (const float*)d_in[5];  const float* be1 = (const float*)d_in[6];
  const float* w1b = (const float*)d_in[7];  const float* b1b = (const float*)d_in[8];
  const float* w2a = (const float*)d_in[9];  const float* b2a = (const float*)d_in[10];
  const float* g2  = (const float*)d_in[11]; const float* be2 = (const float*)d_in[12];
  const float* w2b = (const float*)d_in[13]; const float* b2b = (const float*)d_in[14];
  const float* w3a = (const float*)d_in[15]; const float* b3a = (const float*)d_in[16];
  const float* g3  = (const float*)d_in[17]; const float* be3 = (const float*)d_in[18];
  const float* w3b = (const float*)d_in[19]; const float* b3b = (const float*)d_in[20];
  const float* wh1 = (const float*)d_in[21]; const float* bh1 = (const float*)d_in[22];
  const float* wh2 = (const float*)d_in[23]; const float* bh2 = (const float*)d_in[24];
  float* out = (float*)d_out;

  const int N = in_sizes[0] / 128;   // 50000
  const int E = in_sizes[1] / 2;     // 800000
  const int G = 512;

  // ---- workspace layout (~110 MB) ----
  char* ws = (char*)d_ws;
  size_t off = 0;
  auto alloc = [&](size_t bytes) {
    void* p = ws + off;
    off = (off + bytes + 255) & ~(size_t)255;
    return p;
  };
  float* bufA  = (float*)alloc((size_t)N * 256 * 4);
  float* bufB  = (float*)alloc((size_t)N * 256 * 4);
  int* adj     = (int*)alloc((size_t)E * 4);
  int* rowptr  = (int*)alloc((size_t)(N + 1) * 4);
  int* cursor  = (int*)alloc((size_t)N * 4);
  int* deg     = (int*)alloc((size_t)N * 4);
  unsigned short* wHi = (unsigned short*)alloc(360448 * 2);
  unsigned short* wLo = (unsigned short*)alloc(360448 * 2);
  float* stats = (float*)alloc(512 * 4);
  float* scsh  = (float*)alloc(512 * 4);
  int* gs      = (int*)alloc(G * 4);
  int* ge      = (int*)alloc(G * 4);
  float* pooled = (float*)alloc((size_t)G * 256 * 4);
  float* thid   = (float*)alloc((size_t)G * 512 * 4);

  // transposed-weight element offsets
  const int o1a = 0, o1b = 32768, o2a = 98304, o2b = 163840, o3a = 229376, o3b = 294912;

  hipMemsetAsync(deg, 0, (size_t)N * 4, stream);
  hipMemsetAsync(gs, 0, (size_t)G * 4, stream);
  hipMemsetAsync(ge, 0, (size_t)G * 4, stream);

  int eb = (E + 255) / 256;
  k_hist<<<eb, 256, 0, stream>>>(ei, deg, E);
  k_scan<<<1, 1024, 0, stream>>>(deg, rowptr, cursor, N);
  k_fill<<<eb, 256, 0, stream>>>(ei, cursor, adj, E);

  k_prep<<<128, 256, 0, stream>>>(w1a, wHi + o1a, wLo + o1a, 128);
  k_prep<<<256, 256, 0, stream>>>(w1b, wHi + o1b, wLo + o1b, 256);
  k_prep<<<256, 256, 0, stream>>>(w2a, wHi + o2a, wLo + o2a, 256);
  k_prep<<<256, 256, 0, stream>>>(w2b, wHi + o2b, wLo + o2b, 256);
  k_prep<<<256, 256, 0, stream>>>(w3a, wHi + o3a, wLo + o3a, 256);
  k_prep<<<256, 256, 0, stream>>>(w3b, wHi + o3b, wLo + o3b, 256);

  k_bounds<<<(N + 255) / 256, 256, 0, stream>>>(bat, gs, ge, N);

  int nb4 = (N + 3) / 4;
  dim3 gg((N + 127) / 128, 2);

  // ---- layer 1 ----
  k_agg<128><<<nb4, 256, 0, stream>>>(x, bufA, rowptr, adj, N);
  k_gemm<false, 0><<<gg, 256, 0, stream>>>(bufA, N, 128, wHi + o1a, wLo + o1a, b1a, nullptr, bufB);
  hipMemsetAsync(stats, 0, 512 * 4, stream);
  k_stats<<<256, 256, 0, stream>>>(bufB, stats, N);
  k_finalize<<<1, 256, 0, stream>>>(stats, g1, be1, scsh, N);
  k_gemm<true, 1><<<gg, 256, 0, stream>>>(bufB, N, 256, wHi + o1b, wLo + o1b, b1b, scsh, bufA);

  // ---- layer 2 ----
  k_agg<256><<<nb4, 256, 0, stream>>>(bufA, bufB, rowptr, adj, N);
  k_gemm<false, 0><<<gg, 256, 0, stream>>>(bufB, N, 256, wHi + o2a, wLo + o2a, b2a, nullptr, bufA);
  hipMemsetAsync(stats, 0, 512 * 4, stream);
  k_stats<<<256, 256, 0, stream>>>(bufA, stats, N);
  k_finalize<<<1, 256, 0, stream>>>(stats, g2, be2, scsh, N);
  k_gemm<true, 3><<<gg, 256, 0, stream>>>(bufA, N, 256, wHi + o2b, wLo + o2b, b2b, scsh, bufB);

  // ---- layer 3 ----
  k_agg<256><<<nb4, 256, 0, stream>>>(bufB, bufA, rowptr, adj, N);
  k_gemm<false, 0><<<gg, 256, 0, stream>>>(bufA, N, 256, wHi + o3a, wLo + o3a, b3a, nullptr, bufB);
  hipMemsetAsync(stats, 0, 512 * 4, stream);
  k_stats<<<256, 256, 0, stream>>>(bufB, stats, N);
  k_finalize<<<1, 256, 0, stream>>>(stats, g3, be3, scsh, N);
  k_gemm<true, 2><<<gg, 256, 0, stream>>>(bufB, N, 256, wHi + o3b, wLo + o3b, b3b, scsh, bufA);

  // ---- pool + head ----
  k_pool<<<G, 256, 0, stream>>>(bufA, gs, ge, pooled);
  k_head1<<<G, 256, 0, stream>>>(pooled, wh1, bh1, thid);
  k_head2<<<G, 256, 0, stream>>>(thid, wh2, bh2, out);
}

// Round 3
// 1086.750 us; speedup vs baseline: 1.1291x; 1.1291x over previous
//
#include <hip/hip_runtime.h>

// ---------------------------------------------------------------------------
// GIN GraphEncoder on MI355X.
// Per layer: h = x + CSR-gather-sum(x) -> z = h@Wa + ba (MFMA split-bf16,
// BN stats fused into epilogue) -> fold scale/shift -> out = relu_bn(z)@Wb
// (+tanh/relu epilogue). Then graph mean-pool + 2 MFMA head GEMMs.
// Integer inputs arrive as int32.
// ---------------------------------------------------------------------------

typedef __attribute__((ext_vector_type(8))) short short8;   // 8 bf16 for MFMA
typedef __attribute__((ext_vector_type(4))) float f32x4;
typedef __attribute__((ext_vector_type(4))) unsigned short us4;
typedef __attribute__((ext_vector_type(8))) unsigned short us8;

__device__ __forceinline__ unsigned short f2bf(float f) {
  unsigned int b = __float_as_uint(f);
  unsigned int r = 0x7FFFu + ((b >> 16) & 1u);   // round-to-nearest-even
  return (unsigned short)((b + r) >> 16);
}
__device__ __forceinline__ float bf2f(unsigned short u) {
  return __uint_as_float(((unsigned int)u) << 16);
}

// ---------------- CSR build ----------------
__global__ void k_hist(const int* __restrict__ ei, int* __restrict__ deg, int E) {
  int e = blockIdx.x * 256 + threadIdx.x;
  if (e >= E) return;
  atomicAdd(&deg[ei[E + e]], 1);
}

__global__ __launch_bounds__(1024) void k_scan(const int* __restrict__ deg,
                                               int* __restrict__ rowptr,
                                               int* __restrict__ cursor, int N) {
  __shared__ int sd[1024];
  __shared__ int running;
  int tid = threadIdx.x;
  if (tid == 0) { running = 0; rowptr[0] = 0; }
  __syncthreads();
  int iters = (N + 1023) >> 10;
  for (int it = 0; it < iters; ++it) {
    int i = (it << 10) + tid;
    int v = (i < N) ? deg[i] : 0;
    sd[tid] = v;
    __syncthreads();
    for (int off = 1; off < 1024; off <<= 1) {
      int t = (tid >= off) ? sd[tid - off] : 0;
      __syncthreads();
      sd[tid] += t;
      __syncthreads();
    }
    int roff = running;
    int incl = sd[tid] + roff;
    if (i < N) { rowptr[i + 1] = incl; cursor[i] = incl - v; }
    __syncthreads();
    if (tid == 1023) running = incl;
    __syncthreads();
  }
}

__global__ void k_fill(const int* __restrict__ ei, int* __restrict__ cursor,
                       int* __restrict__ adj, int E) {
  int e = blockIdx.x * 256 + threadIdx.x;
  if (e >= E) return;
  int s = ei[e];
  int d = ei[E + e];
  int pos = atomicAdd(&cursor[d], 1);
  adj[pos] = s;
}

// ---- weight transpose + bf16 hi/lo split: W[K][Nout] -> Wt[Nout][K] ----
__global__ void k_prep(const float* __restrict__ W, unsigned short* __restrict__ Hi,
                       unsigned short* __restrict__ Lo, int K, int Nout) {
  int idx = blockIdx.x * 256 + threadIdx.x;
  if (idx >= K * Nout) return;
  int n = idx % Nout, k = idx / Nout;
  float w = W[k * Nout + n];
  unsigned short h = f2bf(w);
  Hi[n * K + k] = h;
  Lo[n * K + k] = f2bf(w - bf2f(h));
}

// ---------------- aggregation: H[i] = X[i] + sum_{e in CSR(i)} X[adj[e]] ----
template <int C>
__global__ __launch_bounds__(256) void k_agg(const float* __restrict__ X,
                                             float* __restrict__ H,
                                             const int* __restrict__ rowptr,
                                             const int* __restrict__ adj, int N) {
  int node = blockIdx.x * 4 + (threadIdx.x >> 6);
  if (node >= N) return;
  int lane = threadIdx.x & 63;
  int e0 = rowptr[node], e1 = rowptr[node + 1];
  if constexpr (C == 256) {
    float4 acc = ((const float4*)(X + (size_t)node * C))[lane];
    for (int e = e0; e < e1; ++e) {
      int s = adj[e];
      float4 v = ((const float4*)(X + (size_t)s * C))[lane];
      acc.x += v.x; acc.y += v.y; acc.z += v.z; acc.w += v.w;
    }
    ((float4*)(H + (size_t)node * C))[lane] = acc;
  } else {  // C == 128
    float2 acc = ((const float2*)(X + (size_t)node * C))[lane];
    for (int e = e0; e < e1; ++e) {
      int s = adj[e];
      float2 v = ((const float2*)(X + (size_t)s * C))[lane];
      acc.x += v.x; acc.y += v.y;
    }
    ((float2*)(H + (size_t)node * C))[lane] = acc;
  }
}

// ---------------- MFMA GEMM: Out[M][Nld] = f(A[M][K]) @ W[K][Nout] + bias ----
// Split-bf16: acc += aHi*wHi + aHi*wLo + aLo*wHi  (~f32 accuracy).
// BNP: A-load prologue relu(a*scale+shift).
// EPI: 0 none, 1 relu, 2 tanh, 3 relu(tanh).
// STATS: epilogue accumulates per-column sum/sumsq of (acc+bias) into stats[].
template <bool BNP, int EPI, bool STATS>
__global__ __launch_bounds__(256) void k_gemm(const float* __restrict__ A, int M, int K,
                                              int Nld,
                                              const unsigned short* __restrict__ WHi,
                                              const unsigned short* __restrict__ WLo,
                                              const float* __restrict__ bias,
                                              const float* __restrict__ scsh,
                                              float* __restrict__ Out,
                                              float* __restrict__ stats) {
  __shared__ unsigned short aHi[128][56], aLo[128][56];  // pad 32->56: 16B rows, conflict-spread
  __shared__ unsigned short bHi[128][56], bLo[128][56];
  const int tid = threadIdx.x;
  const int lane = tid & 63, w = tid >> 6;
  const int wm = w >> 1, wn = w & 1;
  const int m0 = blockIdx.x * 128;
  const int n0 = blockIdx.y * 128;

  f32x4 zero = {0.f, 0.f, 0.f, 0.f};
  f32x4 acc[4][4];
#pragma unroll
  for (int i = 0; i < 4; ++i)
#pragma unroll
    for (int j = 0; j < 4; ++j) acc[i][j] = zero;

  for (int kb = 0; kb < K; kb += 32) {
    __syncthreads();
    // stage A tile 128x32 f32 -> bf16 hi/lo (optional BN+relu prologue)
#pragma unroll
    for (int q = 0; q < 4; ++q) {
      int idx = tid + q * 256;          // float4 index, 1024 total
      int row = idx >> 3, kq = idx & 7;
      int grow = m0 + row;
      float vv[4] = {0.f, 0.f, 0.f, 0.f};
      if (grow < M) {
        const float4 v = *(const float4*)(A + (size_t)grow * K + kb + kq * 4);
        vv[0] = v.x; vv[1] = v.y; vv[2] = v.z; vv[3] = v.w;
      }
      us4 hv, lv;
#pragma unroll
      for (int j = 0; j < 4; ++j) {
        float f = vv[j];
        if (BNP) {
          int kc = kb + kq * 4 + j;
          f = fmaxf(f * scsh[kc] + scsh[256 + kc], 0.f);
        }
        unsigned short h = f2bf(f);
        hv[j] = h;
        lv[j] = f2bf(f - bf2f(h));
      }
      *(us4*)&aHi[row][kq * 4] = hv;
      *(us4*)&aLo[row][kq * 4] = lv;
    }
    // stage B tile: Wt rows [n0, n0+128) x 32 k, pre-split bf16
#pragma unroll
    for (int q = 0; q < 2; ++q) {
      int idx = tid + q * 256;          // 8-elem chunk index, 512 total
      int nrow = idx >> 2, k8 = idx & 3;
      size_t go = (size_t)(n0 + nrow) * K + kb + k8 * 8;
      *(us8*)&bHi[nrow][k8 * 8] = *(const us8*)(WHi + go);
      *(us8*)&bLo[nrow][k8 * 8] = *(const us8*)(WLo + go);
    }
    __syncthreads();

    const int ko = (lane >> 4) * 8;
    short8 bh[4], bl[4];
#pragma unroll
    for (int ni = 0; ni < 4; ++ni) {
      int r = wn * 64 + ni * 16 + (lane & 15);
      bh[ni] = *(const short8*)&bHi[r][ko];
      bl[ni] = *(const short8*)&bLo[r][ko];
    }
#pragma unroll
    for (int mi = 0; mi < 4; ++mi) {
      int r = wm * 64 + mi * 16 + (lane & 15);
      short8 ah = *(const short8*)&aHi[r][ko];
      short8 al = *(const short8*)&aLo[r][ko];
#pragma unroll
      for (int ni = 0; ni < 4; ++ni) {
        acc[mi][ni] = __builtin_amdgcn_mfma_f32_16x16x32_bf16(ah, bh[ni], acc[mi][ni], 0, 0, 0);
        acc[mi][ni] = __builtin_amdgcn_mfma_f32_16x16x32_bf16(ah, bl[ni], acc[mi][ni], 0, 0, 0);
        acc[mi][ni] = __builtin_amdgcn_mfma_f32_16x16x32_bf16(al, bh[ni], acc[mi][ni], 0, 0, 0);
      }
    }
  }

  // epilogue: C/D layout col = lane&15, row = (lane>>4)*4 + r   [m89-verified]
#pragma unroll
  for (int ni = 0; ni < 4; ++ni) {
    int col = n0 + wn * 64 + ni * 16 + (lane & 15);
    float bc = bias[col];
    float s = 0.f, q = 0.f;
#pragma unroll
    for (int mi = 0; mi < 4; ++mi) {
      int rbase = m0 + wm * 64 + mi * 16 + (lane >> 4) * 4;
#pragma unroll
      for (int r = 0; r < 4; ++r) {
        int row = rbase + r;
        if (row < M) {
          float o = acc[mi][ni][r] + bc;
          if (STATS) { s += o; q += o * o; }
          if (EPI == 1) o = fmaxf(o, 0.f);
          else if (EPI == 2) o = tanhf(o);
          else if (EPI == 3) o = fmaxf(tanhf(o), 0.f);
          Out[(size_t)row * Nld + col] = o;
        }
      }
    }
    if (STATS) {
      // reduce across the 4 lane-groups (lane>>4) holding the same column
      s += __shfl_xor(s, 16); s += __shfl_xor(s, 32);
      q += __shfl_xor(q, 16); q += __shfl_xor(q, 32);
      if ((lane >> 4) == 0) {
        atomicAdd(&stats[col], s);
        atomicAdd(&stats[256 + col], q);
      }
    }
  }
}

__global__ void k_finalize(const float* __restrict__ stats, const float* __restrict__ g,
                           const float* __restrict__ be, float* __restrict__ scsh, int M) {
  int c = threadIdx.x;
  float mu = stats[c] / (float)M;
  float var = stats[256 + c] / (float)M - mu * mu;
  float sc = g[c] * rsqrtf(var + 1e-5f);
  scsh[c] = sc;
  scsh[256 + c] = be[c] - mu * sc;
}

// ---------------- pooling ----------------
__global__ void k_bounds(const int* __restrict__ batch, int* __restrict__ gs,
                         int* __restrict__ ge, int N) {
  int i = blockIdx.x * 256 + threadIdx.x;
  if (i >= N) return;
  int b = batch[i];
  if (i == 0 || batch[i - 1] != b) gs[b] = i;
  if (i == N - 1 || batch[i + 1] != b) ge[b] = i + 1;
}

__global__ __launch_bounds__(256) void k_pool(const float* __restrict__ Hf,
                                              const int* __restrict__ gs,
                                              const int* __restrict__ ge,
                                              float* __restrict__ pooled) {
  int g = blockIdx.x;
  int s = gs[g], e = ge[g];
  float acc = 0.f;
  for (int r = s; r < e; ++r) acc += Hf[(size_t)r * 256 + threadIdx.x];
  pooled[g * 256 + threadIdx.x] = acc / fmaxf((float)(e - s), 1.0f);
}

// ---------------------------------------------------------------------------
extern "C" void kernel_launch(void* const* d_in, const int* in_sizes, int n_in,
                              void* d_out, int out_size, void* d_ws, size_t ws_size,
                              hipStream_t stream) {
  const float* x      = (const float*)d_in[0];
  const int* ei       = (const int*)d_in[1];    // int32 from harness
  const int* bat      = (const int*)d_in[2];    // int32 from harness
  const float* w1a = (const float*)d_in[3];  const float* b1a = (const float*)d_in[4];
  const float* g1  = (const float*)d_in[5];  const float* be1 = (const float*)d_in[6];
  const float* w1b = (const float*)d_in[7];  const float* b1b = (const float*)d_in[8];
  const float* w2a = (const float*)d_in[9];  const float* b2a = (const float*)d_in[10];
  const float* g2  = (const float*)d_in[11]; const float* be2 = (const float*)d_in[12];
  const float* w2b = (const float*)d_in[13]; const float* b2b = (const float*)d_in[14];
  const float* w3a = (const float*)d_in[15]; const float* b3a = (const float*)d_in[16];
  const float* g3  = (const float*)d_in[17]; const float* be3 = (const float*)d_in[18];
  const float* w3b = (const float*)d_in[19]; const float* b3b = (const float*)d_in[20];
  const float* wh1 = (const float*)d_in[21]; const float* bh1 = (const float*)d_in[22];
  const float* wh2 = (const float*)d_in[23]; const float* bh2 = (const float*)d_in[24];
  float* out = (float*)d_out;

  const int N = in_sizes[0] / 128;   // 50000
  const int E = in_sizes[1] / 2;     // 800000
  const int G = 512;

  // ---- workspace layout ----
  char* ws = (char*)d_ws;
  size_t off = 0;
  auto alloc = [&](size_t bytes) {
    void* p = ws + off;
    off = (off + bytes + 255) & ~(size_t)255;
    return p;
  };
  float* bufA  = (float*)alloc((size_t)N * 256 * 4);
  float* bufB  = (float*)alloc((size_t)N * 256 * 4);
  int* adj     = (int*)alloc((size_t)E * 4);
  int* rowptr  = (int*)alloc((size_t)(N + 1) * 4);
  int* cursor  = (int*)alloc((size_t)N * 4);
  int* deg     = (int*)alloc((size_t)N * 4);
  unsigned short* wHi = (unsigned short*)alloc(884736 * 2);
  unsigned short* wLo = (unsigned short*)alloc(884736 * 2);
  float* stats = (float*)alloc(512 * 4);
  float* scsh  = (float*)alloc(512 * 4);
  int* gs      = (int*)alloc(G * 4);
  int* ge      = (int*)alloc(G * 4);
  float* pooled = (float*)alloc((size_t)G * 256 * 4);
  float* thid   = (float*)alloc((size_t)G * 512 * 4);

  // transposed-weight element offsets
  const int o1a = 0, o1b = 32768, o2a = 98304, o2b = 163840, o3a = 229376, o3b = 294912;
  const int oh1 = 360448, oh2 = 491520;   // ends at 884736

  hipMemsetAsync(deg, 0, (size_t)N * 4, stream);
  hipMemsetAsync(gs, 0, (size_t)G * 4, stream);
  hipMemsetAsync(ge, 0, (size_t)G * 4, stream);

  int eb = (E + 255) / 256;
  k_hist<<<eb, 256, 0, stream>>>(ei, deg, E);
  k_scan<<<1, 1024, 0, stream>>>(deg, rowptr, cursor, N);
  k_fill<<<eb, 256, 0, stream>>>(ei, cursor, adj, E);

  k_prep<<<128, 256, 0, stream>>>(w1a, wHi + o1a, wLo + o1a, 128, 256);
  k_prep<<<256, 256, 0, stream>>>(w1b, wHi + o1b, wLo + o1b, 256, 256);
  k_prep<<<256, 256, 0, stream>>>(w2a, wHi + o2a, wLo + o2a, 256, 256);
  k_prep<<<256, 256, 0, stream>>>(w2b, wHi + o2b, wLo + o2b, 256, 256);
  k_prep<<<256, 256, 0, stream>>>(w3a, wHi + o3a, wLo + o3a, 256, 256);
  k_prep<<<256, 256, 0, stream>>>(w3b, wHi + o3b, wLo + o3b, 256, 256);
  k_prep<<<512, 256, 0, stream>>>(wh1, wHi + oh1, wLo + oh1, 256, 512);
  k_prep<<<1536, 256, 0, stream>>>(wh2, wHi + oh2, wLo + oh2, 512, 768);

  k_bounds<<<(N + 255) / 256, 256, 0, stream>>>(bat, gs, ge, N);

  int nb4 = (N + 3) / 4;
  dim3 gg((N + 127) / 128, 2);

  // ---- layer 1 ----
  k_agg<128><<<nb4, 256, 0, stream>>>(x, bufA, rowptr, adj, N);
  hipMemsetAsync(stats, 0, 512 * 4, stream);
  k_gemm<false, 0, true><<<gg, 256, 0, stream>>>(bufA, N, 128, 256, wHi + o1a, wLo + o1a, b1a, nullptr, bufB, stats);
  k_finalize<<<1, 256, 0, stream>>>(stats, g1, be1, scsh, N);
  k_gemm<true, 1, false><<<gg, 256, 0, stream>>>(bufB, N, 256, 256, wHi + o1b, wLo + o1b, b1b, scsh, bufA, nullptr);

  // ---- layer 2 ----
  k_agg<256><<<nb4, 256, 0, stream>>>(bufA, bufB, rowptr, adj, N);
  hipMemsetAsync(stats, 0, 512 * 4, stream);
  k_gemm<false, 0, true><<<gg, 256, 0, stream>>>(bufB, N, 256, 256, wHi + o2a, wLo + o2a, b2a, nullptr, bufA, stats);
  k_finalize<<<1, 256, 0, stream>>>(stats, g2, be2, scsh, N);
  k_gemm<true, 3, false><<<gg, 256, 0, stream>>>(bufA, N, 256, 256, wHi + o2b, wLo + o2b, b2b, scsh, bufB, nullptr);

  // ---- layer 3 ----
  k_agg<256><<<nb4, 256, 0, stream>>>(bufB, bufA, rowptr, adj, N);
  hipMemsetAsync(stats, 0, 512 * 4, stream);
  k_gemm<false, 0, true><<<gg, 256, 0, stream>>>(bufA, N, 256, 256, wHi + o3a, wLo + o3a, b3a, nullptr, bufB, stats);
  k_finalize<<<1, 256, 0, stream>>>(stats, g3, be3, scsh, N);
  k_gemm<true, 2, false><<<gg, 256, 0, stream>>>(bufB, N, 256, 256, wHi + o3b, wLo + o3b, b3b, scsh, bufA, nullptr);

  // ---- pool + MFMA heads ----
  k_pool<<<G, 256, 0, stream>>>(bufA, gs, ge, pooled);
  dim3 gh1(4, 4);   // M=512/128, N=512/128
  k_gemm<false, 1, false><<<gh1, 256, 0, stream>>>(pooled, G, 256, 512, wHi + oh1, wLo + oh1, bh1, nullptr, thid, nullptr);
  dim3 gh2(4, 6);   // M=512/128, N=768/128
  k_gemm<false, 0, false><<<gh2, 256, 0, stream>>>(thid, G, 512, 768, wHi + oh2, wLo + oh2, bh2, nullptr, out, nullptr);
}

// Round 4
// 1058.554 us; speedup vs baseline: 1.1592x; 1.0266x over previous
//
#include <hip/hip_runtime.h>

// ---------------------------------------------------------------------------
// GIN GraphEncoder on MI355X.
// Per layer: h = x + CSR-gather-sum(x) -> z = h@Wa + ba (MFMA split-bf16,
// BN stats fused into epilogue) -> fold scale/shift -> out = relu_bn(z)@Wb
// (+tanh/relu epilogue). Then graph mean-pool + 2 MFMA head GEMMs.
// Integer inputs arrive as int32.
// R4: k_agg edge loop unrolled x4 (4 gathers in flight -> latency hiding).
// ---------------------------------------------------------------------------

typedef __attribute__((ext_vector_type(8))) short short8;   // 8 bf16 for MFMA
typedef __attribute__((ext_vector_type(4))) float f32x4;
typedef __attribute__((ext_vector_type(4))) unsigned short us4;
typedef __attribute__((ext_vector_type(8))) unsigned short us8;

__device__ __forceinline__ unsigned short f2bf(float f) {
  unsigned int b = __float_as_uint(f);
  unsigned int r = 0x7FFFu + ((b >> 16) & 1u);   // round-to-nearest-even
  return (unsigned short)((b + r) >> 16);
}
__device__ __forceinline__ float bf2f(unsigned short u) {
  return __uint_as_float(((unsigned int)u) << 16);
}

// ---------------- CSR build ----------------
__global__ void k_hist(const int* __restrict__ ei, int* __restrict__ deg, int E) {
  int e = blockIdx.x * 256 + threadIdx.x;
  if (e >= E) return;
  atomicAdd(&deg[ei[E + e]], 1);
}

__global__ __launch_bounds__(1024) void k_scan(const int* __restrict__ deg,
                                               int* __restrict__ rowptr,
                                               int* __restrict__ cursor, int N) {
  __shared__ int sd[1024];
  __shared__ int running;
  int tid = threadIdx.x;
  if (tid == 0) { running = 0; rowptr[0] = 0; }
  __syncthreads();
  int iters = (N + 1023) >> 10;
  for (int it = 0; it < iters; ++it) {
    int i = (it << 10) + tid;
    int v = (i < N) ? deg[i] : 0;
    sd[tid] = v;
    __syncthreads();
    for (int off = 1; off < 1024; off <<= 1) {
      int t = (tid >= off) ? sd[tid - off] : 0;
      __syncthreads();
      sd[tid] += t;
      __syncthreads();
    }
    int roff = running;
    int incl = sd[tid] + roff;
    if (i < N) { rowptr[i + 1] = incl; cursor[i] = incl - v; }
    __syncthreads();
    if (tid == 1023) running = incl;
    __syncthreads();
  }
}

__global__ void k_fill(const int* __restrict__ ei, int* __restrict__ cursor,
                       int* __restrict__ adj, int E) {
  int e = blockIdx.x * 256 + threadIdx.x;
  if (e >= E) return;
  int s = ei[e];
  int d = ei[E + e];
  int pos = atomicAdd(&cursor[d], 1);
  adj[pos] = s;
}

// ---- weight transpose + bf16 hi/lo split: W[K][Nout] -> Wt[Nout][K] ----
__global__ void k_prep(const float* __restrict__ W, unsigned short* __restrict__ Hi,
                       unsigned short* __restrict__ Lo, int K, int Nout) {
  int idx = blockIdx.x * 256 + threadIdx.x;
  if (idx >= K * Nout) return;
  int n = idx % Nout, k = idx / Nout;
  float w = W[k * Nout + n];
  unsigned short h = f2bf(w);
  Hi[n * K + k] = h;
  Lo[n * K + k] = f2bf(w - bf2f(h));
}

// ---------------- aggregation: H[i] = X[i] + sum_{e in CSR(i)} X[adj[e]] ----
// Edge loop unrolled x4: 4 independent row-gathers in flight per wave.
template <int C>
__global__ __launch_bounds__(256) void k_agg(const float* __restrict__ X,
                                             float* __restrict__ H,
                                             const int* __restrict__ rowptr,
                                             const int* __restrict__ adj, int N) {
  int node = blockIdx.x * 4 + (threadIdx.x >> 6);
  if (node >= N) return;
  int lane = threadIdx.x & 63;
  int e0 = rowptr[node], e1 = rowptr[node + 1];
  if constexpr (C == 256) {
    float4 acc = ((const float4*)(X + (size_t)node * C))[lane];
    int e = e0;
    for (; e + 4 <= e1; e += 4) {
      int s0 = adj[e], s1 = adj[e + 1], s2 = adj[e + 2], s3 = adj[e + 3];
      float4 v0 = ((const float4*)(X + (size_t)s0 * C))[lane];
      float4 v1 = ((const float4*)(X + (size_t)s1 * C))[lane];
      float4 v2 = ((const float4*)(X + (size_t)s2 * C))[lane];
      float4 v3 = ((const float4*)(X + (size_t)s3 * C))[lane];
      acc.x += (v0.x + v1.x) + (v2.x + v3.x);
      acc.y += (v0.y + v1.y) + (v2.y + v3.y);
      acc.z += (v0.z + v1.z) + (v2.z + v3.z);
      acc.w += (v0.w + v1.w) + (v2.w + v3.w);
    }
    for (; e < e1; ++e) {
      int s = adj[e];
      float4 v = ((const float4*)(X + (size_t)s * C))[lane];
      acc.x += v.x; acc.y += v.y; acc.z += v.z; acc.w += v.w;
    }
    ((float4*)(H + (size_t)node * C))[lane] = acc;
  } else {  // C == 128
    float2 acc = ((const float2*)(X + (size_t)node * C))[lane];
    int e = e0;
    for (; e + 4 <= e1; e += 4) {
      int s0 = adj[e], s1 = adj[e + 1], s2 = adj[e + 2], s3 = adj[e + 3];
      float2 v0 = ((const float2*)(X + (size_t)s0 * C))[lane];
      float2 v1 = ((const float2*)(X + (size_t)s1 * C))[lane];
      float2 v2 = ((const float2*)(X + (size_t)s2 * C))[lane];
      float2 v3 = ((const float2*)(X + (size_t)s3 * C))[lane];
      acc.x += (v0.x + v1.x) + (v2.x + v3.x);
      acc.y += (v0.y + v1.y) + (v2.y + v3.y);
    }
    for (; e < e1; ++e) {
      int s = adj[e];
      float2 v = ((const float2*)(X + (size_t)s * C))[lane];
      acc.x += v.x; acc.y += v.y;
    }
    ((float2*)(H + (size_t)node * C))[lane] = acc;
  }
}

// ---------------- MFMA GEMM: Out[M][Nld] = f(A[M][K]) @ W[K][Nout] + bias ----
// Split-bf16: acc += aHi*wHi + aHi*wLo + aLo*wHi  (~f32 accuracy).
// BNP: A-load prologue relu(a*scale+shift).
// EPI: 0 none, 1 relu, 2 tanh, 3 relu(tanh).
// STATS: epilogue accumulates per-column sum/sumsq of (acc+bias) into stats[].
template <bool BNP, int EPI, bool STATS>
__global__ __launch_bounds__(256) void k_gemm(const float* __restrict__ A, int M, int K,
                                              int Nld,
                                              const unsigned short* __restrict__ WHi,
                                              const unsigned short* __restrict__ WLo,
                                              const float* __restrict__ bias,
                                              const float* __restrict__ scsh,
                                              float* __restrict__ Out,
                                              float* __restrict__ stats) {
  __shared__ unsigned short aHi[128][56], aLo[128][56];  // pad 32->56: 16B rows, conflict-spread
  __shared__ unsigned short bHi[128][56], bLo[128][56];
  const int tid = threadIdx.x;
  const int lane = tid & 63, w = tid >> 6;
  const int wm = w >> 1, wn = w & 1;
  const int m0 = blockIdx.x * 128;
  const int n0 = blockIdx.y * 128;

  f32x4 zero = {0.f, 0.f, 0.f, 0.f};
  f32x4 acc[4][4];
#pragma unroll
  for (int i = 0; i < 4; ++i)
#pragma unroll
    for (int j = 0; j < 4; ++j) acc[i][j] = zero;

  for (int kb = 0; kb < K; kb += 32) {
    __syncthreads();
    // stage A tile 128x32 f32 -> bf16 hi/lo (optional BN+relu prologue)
#pragma unroll
    for (int q = 0; q < 4; ++q) {
      int idx = tid + q * 256;          // float4 index, 1024 total
      int row = idx >> 3, kq = idx & 7;
      int grow = m0 + row;
      float vv[4] = {0.f, 0.f, 0.f, 0.f};
      if (grow < M) {
        const float4 v = *(const float4*)(A + (size_t)grow * K + kb + kq * 4);
        vv[0] = v.x; vv[1] = v.y; vv[2] = v.z; vv[3] = v.w;
      }
      us4 hv, lv;
#pragma unroll
      for (int j = 0; j < 4; ++j) {
        float f = vv[j];
        if (BNP) {
          int kc = kb + kq * 4 + j;
          f = fmaxf(f * scsh[kc] + scsh[256 + kc], 0.f);
        }
        unsigned short h = f2bf(f);
        hv[j] = h;
        lv[j] = f2bf(f - bf2f(h));
      }
      *(us4*)&aHi[row][kq * 4] = hv;
      *(us4*)&aLo[row][kq * 4] = lv;
    }
    // stage B tile: Wt rows [n0, n0+128) x 32 k, pre-split bf16
#pragma unroll
    for (int q = 0; q < 2; ++q) {
      int idx = tid + q * 256;          // 8-elem chunk index, 512 total
      int nrow = idx >> 2, k8 = idx & 3;
      size_t go = (size_t)(n0 + nrow) * K + kb + k8 * 8;
      *(us8*)&bHi[nrow][k8 * 8] = *(const us8*)(WHi + go);
      *(us8*)&bLo[nrow][k8 * 8] = *(const us8*)(WLo + go);
    }
    __syncthreads();

    const int ko = (lane >> 4) * 8;
    short8 bh[4], bl[4];
#pragma unroll
    for (int ni = 0; ni < 4; ++ni) {
      int r = wn * 64 + ni * 16 + (lane & 15);
      bh[ni] = *(const short8*)&bHi[r][ko];
      bl[ni] = *(const short8*)&bLo[r][ko];
    }
#pragma unroll
    for (int mi = 0; mi < 4; ++mi) {
      int r = wm * 64 + mi * 16 + (lane & 15);
      short8 ah = *(const short8*)&aHi[r][ko];
      short8 al = *(const short8*)&aLo[r][ko];
#pragma unroll
      for (int ni = 0; ni < 4; ++ni) {
        acc[mi][ni] = __builtin_amdgcn_mfma_f32_16x16x32_bf16(ah, bh[ni], acc[mi][ni], 0, 0, 0);
        acc[mi][ni] = __builtin_amdgcn_mfma_f32_16x16x32_bf16(ah, bl[ni], acc[mi][ni], 0, 0, 0);
        acc[mi][ni] = __builtin_amdgcn_mfma_f32_16x16x32_bf16(al, bh[ni], acc[mi][ni], 0, 0, 0);
      }
    }
  }

  // epilogue: C/D layout col = lane&15, row = (lane>>4)*4 + r   [m89-verified]
#pragma unroll
  for (int ni = 0; ni < 4; ++ni) {
    int col = n0 + wn * 64 + ni * 16 + (lane & 15);
    float bc = bias[col];
    float s = 0.f, q = 0.f;
#pragma unroll
    for (int mi = 0; mi < 4; ++mi) {
      int rbase = m0 + wm * 64 + mi * 16 + (lane >> 4) * 4;
#pragma unroll
      for (int r = 0; r < 4; ++r) {
        int row = rbase + r;
        if (row < M) {
          float o = acc[mi][ni][r] + bc;
          if (STATS) { s += o; q += o * o; }
          if (EPI == 1) o = fmaxf(o, 0.f);
          else if (EPI == 2) o = tanhf(o);
          else if (EPI == 3) o = fmaxf(tanhf(o), 0.f);
          Out[(size_t)row * Nld + col] = o;
        }
      }
    }
    if (STATS) {
      // reduce across the 4 lane-groups (lane>>4) holding the same column
      s += __shfl_xor(s, 16); s += __shfl_xor(s, 32);
      q += __shfl_xor(q, 16); q += __shfl_xor(q, 32);
      if ((lane >> 4) == 0) {
        atomicAdd(&stats[col], s);
        atomicAdd(&stats[256 + col], q);
      }
    }
  }
}

__global__ void k_finalize(const float* __restrict__ stats, const float* __restrict__ g,
                           const float* __restrict__ be, float* __restrict__ scsh, int M) {
  int c = threadIdx.x;
  float mu = stats[c] / (float)M;
  float var = stats[256 + c] / (float)M - mu * mu;
  float sc = g[c] * rsqrtf(var + 1e-5f);
  scsh[c] = sc;
  scsh[256 + c] = be[c] - mu * sc;
}

// ---------------- pooling ----------------
__global__ void k_bounds(const int* __restrict__ batch, int* __restrict__ gs,
                         int* __restrict__ ge, int N) {
  int i = blockIdx.x * 256 + threadIdx.x;
  if (i >= N) return;
  int b = batch[i];
  if (i == 0 || batch[i - 1] != b) gs[b] = i;
  if (i == N - 1 || batch[i + 1] != b) ge[b] = i + 1;
}

__global__ __launch_bounds__(256) void k_pool(const float* __restrict__ Hf,
                                              const int* __restrict__ gs,
                                              const int* __restrict__ ge,
                                              float* __restrict__ pooled) {
  int g = blockIdx.x;
  int s = gs[g], e = ge[g];
  float acc = 0.f;
  for (int r = s; r < e; ++r) acc += Hf[(size_t)r * 256 + threadIdx.x];
  pooled[g * 256 + threadIdx.x] = acc / fmaxf((float)(e - s), 1.0f);
}

// ---------------------------------------------------------------------------
extern "C" void kernel_launch(void* const* d_in, const int* in_sizes, int n_in,
                              void* d_out, int out_size, void* d_ws, size_t ws_size,
                              hipStream_t stream) {
  const float* x      = (const float*)d_in[0];
  const int* ei       = (const int*)d_in[1];    // int32 from harness
  const int* bat      = (const int*)d_in[2];    // int32 from harness
  const float* w1a = (const float*)d_in[3];  const float* b1a = (const float*)d_in[4];
  const float* g1  = (const float*)d_in[5];  const float* be1 = (const float*)d_in[6];
  const float* w1b = (const float*)d_in[7];  const float* b1b = (const float*)d_in[8];
  const float* w2a = (const float*)d_in[9];  const float* b2a = (const float*)d_in[10];
  const float* g2  = (const float*)d_in[11]; const float* be2 = (const float*)d_in[12];
  const float* w2b = (const float*)d_in[13]; const float* b2b = (const float*)d_in[14];
  const float* w3a = (const float*)d_in[15]; const float* b3a = (const float*)d_in[16];
  const float* g3  = (const float*)d_in[17]; const float* be3 = (const float*)d_in[18];
  const float* w3b = (const float*)d_in[19]; const float* b3b = (const float*)d_in[20];
  const float* wh1 = (const float*)d_in[21]; const float* bh1 = (const float*)d_in[22];
  const float* wh2 = (const float*)d_in[23]; const float* bh2 = (const float*)d_in[24];
  float* out = (float*)d_out;

  const int N = in_sizes[0] / 128;   // 50000
  const int E = in_sizes[1] / 2;     // 800000
  const int G = 512;

  // ---- workspace layout ----
  char* ws = (char*)d_ws;
  size_t off = 0;
  auto alloc = [&](size_t bytes) {
    void* p = ws + off;
    off = (off + bytes + 255) & ~(size_t)255;
    return p;
  };
  float* bufA  = (float*)alloc((size_t)N * 256 * 4);
  float* bufB  = (float*)alloc((size_t)N * 256 * 4);
  int* adj     = (int*)alloc((size_t)E * 4);
  int* rowptr  = (int*)alloc((size_t)(N + 1) * 4);
  int* cursor  = (int*)alloc((size_t)N * 4);
  int* deg     = (int*)alloc((size_t)N * 4);
  unsigned short* wHi = (unsigned short*)alloc(884736 * 2);
  unsigned short* wLo = (unsigned short*)alloc(884736 * 2);
  float* stats = (float*)alloc(512 * 4);
  float* scsh  = (float*)alloc(512 * 4);
  int* gs      = (int*)alloc(G * 4);
  int* ge      = (int*)alloc(G * 4);
  float* pooled = (float*)alloc((size_t)G * 256 * 4);
  float* thid   = (float*)alloc((size_t)G * 512 * 4);

  // transposed-weight element offsets
  const int o1a = 0, o1b = 32768, o2a = 98304, o2b = 163840, o3a = 229376, o3b = 294912;
  const int oh1 = 360448, oh2 = 491520;   // ends at 884736

  hipMemsetAsync(deg, 0, (size_t)N * 4, stream);
  hipMemsetAsync(gs, 0, (size_t)G * 4, stream);
  hipMemsetAsync(ge, 0, (size_t)G * 4, stream);

  int eb = (E + 255) / 256;
  k_hist<<<eb, 256, 0, stream>>>(ei, deg, E);
  k_scan<<<1, 1024, 0, stream>>>(deg, rowptr, cursor, N);
  k_fill<<<eb, 256, 0, stream>>>(ei, cursor, adj, E);

  k_prep<<<128, 256, 0, stream>>>(w1a, wHi + o1a, wLo + o1a, 128, 256);
  k_prep<<<256, 256, 0, stream>>>(w1b, wHi + o1b, wLo + o1b, 256, 256);
  k_prep<<<256, 256, 0, stream>>>(w2a, wHi + o2a, wLo + o2a, 256, 256);
  k_prep<<<256, 256, 0, stream>>>(w2b, wHi + o2b, wLo + o2b, 256, 256);
  k_prep<<<256, 256, 0, stream>>>(w3a, wHi + o3a, wLo + o3a, 256, 256);
  k_prep<<<256, 256, 0, stream>>>(w3b, wHi + o3b, wLo + o3b, 256, 256);
  k_prep<<<512, 256, 0, stream>>>(wh1, wHi + oh1, wLo + oh1, 256, 512);
  k_prep<<<1536, 256, 0, stream>>>(wh2, wHi + oh2, wLo + oh2, 512, 768);

  k_bounds<<<(N + 255) / 256, 256, 0, stream>>>(bat, gs, ge, N);

  int nb4 = (N + 3) / 4;
  dim3 gg((N + 127) / 128, 2);

  // ---- layer 1 ----
  k_agg<128><<<nb4, 256, 0, stream>>>(x, bufA, rowptr, adj, N);
  hipMemsetAsync(stats, 0, 512 * 4, stream);
  k_gemm<false, 0, true><<<gg, 256, 0, stream>>>(bufA, N, 128, 256, wHi + o1a, wLo + o1a, b1a, nullptr, bufB, stats);
  k_finalize<<<1, 256, 0, stream>>>(stats, g1, be1, scsh, N);
  k_gemm<true, 1, false><<<gg, 256, 0, stream>>>(bufB, N, 256, 256, wHi + o1b, wLo + o1b, b1b, scsh, bufA, nullptr);

  // ---- layer 2 ----
  k_agg<256><<<nb4, 256, 0, stream>>>(bufA, bufB, rowptr, adj, N);
  hipMemsetAsync(stats, 0, 512 * 4, stream);
  k_gemm<false, 0, true><<<gg, 256, 0, stream>>>(bufB, N, 256, 256, wHi + o2a, wLo + o2a, b2a, nullptr, bufA, stats);
  k_finalize<<<1, 256, 0, stream>>>(stats, g2, be2, scsh, N);
  k_gemm<true, 3, false><<<gg, 256, 0, stream>>>(bufA, N, 256, 256, wHi + o2b, wLo + o2b, b2b, scsh, bufB, nullptr);

  // ---- layer 3 ----
  k_agg<256><<<nb4, 256, 0, stream>>>(bufB, bufA, rowptr, adj, N);
  hipMemsetAsync(stats, 0, 512 * 4, stream);
  k_gemm<false, 0, true><<<gg, 256, 0, stream>>>(bufA, N, 256, 256, wHi + o3a, wLo + o3a, b3a, nullptr, bufB, stats);
  k_finalize<<<1, 256, 0, stream>>>(stats, g3, be3, scsh, N);
  k_gemm<true, 2, false><<<gg, 256, 0, stream>>>(bufB, N, 256, 256, wHi + o3b, wLo + o3b, b3b, scsh, bufA, nullptr);

  // ---- pool + MFMA heads ----
  k_pool<<<G, 256, 0, stream>>>(bufA, gs, ge, pooled);
  dim3 gh1(4, 4);   // M=512/128, N=512/128
  k_gemm<false, 1, false><<<gh1, 256, 0, stream>>>(pooled, G, 256, 512, wHi + oh1, wLo + oh1, bh1, nullptr, thid, nullptr);
  dim3 gh2(4, 6);   // M=512/128, N=768/128
  k_gemm<false, 0, false><<<gh2, 256, 0, stream>>>(thid, G, 512, 768, wHi + oh2, wLo + oh2, bh2, nullptr, out, nullptr);
}

// Round 5
// 1007.410 us; speedup vs baseline: 1.2181x; 1.0508x over previous
//
#include <hip/hip_runtime.h>

// ---------------------------------------------------------------------------
// GIN GraphEncoder on MI355X.
// Per layer: h = x + CSR-gather-sum(x) [written as pre-split bf16 hi/lo]
//   -> z = h@Wa + ba (MFMA split-bf16 3-product, BN stats fused in epilogue)
//   -> fold scale/shift -> out = relu_bn(z)@Wb (+tanh/relu epilogue).
// Then graph mean-pool + 2 MFMA head GEMMs.
// Memory: two 51MB regions ping-pong roles (f32 act | split hi/lo | z).
// Integer inputs arrive as int32.
// ---------------------------------------------------------------------------

typedef __attribute__((ext_vector_type(8))) short short8;   // 8 bf16 for MFMA
typedef __attribute__((ext_vector_type(4))) float f32x4;
typedef __attribute__((ext_vector_type(4))) unsigned short us4;
typedef __attribute__((ext_vector_type(8))) unsigned short us8;

__device__ __forceinline__ unsigned short f2bf(float f) {
  unsigned int b = __float_as_uint(f);
  unsigned int r = 0x7FFFu + ((b >> 16) & 1u);   // round-to-nearest-even
  return (unsigned short)((b + r) >> 16);
}
__device__ __forceinline__ float bf2f(unsigned short u) {
  return __uint_as_float(((unsigned int)u) << 16);
}

// ---------------- CSR build ----------------
__global__ void k_hist(const int* __restrict__ ei, int* __restrict__ deg, int E) {
  int e = blockIdx.x * 256 + threadIdx.x;
  if (e >= E) return;
  atomicAdd(&deg[ei[E + e]], 1);
}

__global__ __launch_bounds__(1024) void k_scan(const int* __restrict__ deg,
                                               int* __restrict__ rowptr,
                                               int* __restrict__ cursor, int N) {
  __shared__ int sd[1024];
  __shared__ int running;
  int tid = threadIdx.x;
  if (tid == 0) { running = 0; rowptr[0] = 0; }
  __syncthreads();
  int iters = (N + 1023) >> 10;
  for (int it = 0; it < iters; ++it) {
    int i = (it << 10) + tid;
    int v = (i < N) ? deg[i] : 0;
    sd[tid] = v;
    __syncthreads();
    for (int off = 1; off < 1024; off <<= 1) {
      int t = (tid >= off) ? sd[tid - off] : 0;
      __syncthreads();
      sd[tid] += t;
      __syncthreads();
    }
    int roff = running;
    int incl = sd[tid] + roff;
    if (i < N) { rowptr[i + 1] = incl; cursor[i] = incl - v; }
    __syncthreads();
    if (tid == 1023) running = incl;
    __syncthreads();
  }
}

__global__ void k_fill(const int* __restrict__ ei, int* __restrict__ cursor,
                       int* __restrict__ adj, int E) {
  int e = blockIdx.x * 256 + threadIdx.x;
  if (e >= E) return;
  int s = ei[e];
  int d = ei[E + e];
  int pos = atomicAdd(&cursor[d], 1);
  adj[pos] = s;
}

// ---- weight transpose + bf16 hi/lo split: W[K][Nout] -> Wt[Nout][K] ----
__global__ void k_prep(const float* __restrict__ W, unsigned short* __restrict__ Hi,
                       unsigned short* __restrict__ Lo, int K, int Nout) {
  int idx = blockIdx.x * 256 + threadIdx.x;
  if (idx >= K * Nout) return;
  int n = idx % Nout, k = idx / Nout;
  float w = W[k * Nout + n];
  unsigned short h = f2bf(w);
  Hi[n * K + k] = h;
  Lo[n * K + k] = f2bf(w - bf2f(h));
}

// ---------------- aggregation: h = X[i] + sum X[adj[e]], write hi/lo split --
template <int C>
__global__ __launch_bounds__(256) void k_agg(const float* __restrict__ X,
                                             unsigned short* __restrict__ HHi,
                                             unsigned short* __restrict__ HLo,
                                             const int* __restrict__ rowptr,
                                             const int* __restrict__ adj, int N) {
  int node = blockIdx.x * 4 + (threadIdx.x >> 6);
  if (node >= N) return;
  int lane = threadIdx.x & 63;
  int e0 = rowptr[node], e1 = rowptr[node + 1];
  if constexpr (C == 256) {
    float4 acc = ((const float4*)(X + (size_t)node * C))[lane];
    int e = e0;
    for (; e + 4 <= e1; e += 4) {
      int s0 = adj[e], s1 = adj[e + 1], s2 = adj[e + 2], s3 = adj[e + 3];
      float4 v0 = ((const float4*)(X + (size_t)s0 * C))[lane];
      float4 v1 = ((const float4*)(X + (size_t)s1 * C))[lane];
      float4 v2 = ((const float4*)(X + (size_t)s2 * C))[lane];
      float4 v3 = ((const float4*)(X + (size_t)s3 * C))[lane];
      acc.x += (v0.x + v1.x) + (v2.x + v3.x);
      acc.y += (v0.y + v1.y) + (v2.y + v3.y);
      acc.z += (v0.z + v1.z) + (v2.z + v3.z);
      acc.w += (v0.w + v1.w) + (v2.w + v3.w);
    }
    for (; e < e1; ++e) {
      int s = adj[e];
      float4 v = ((const float4*)(X + (size_t)s * C))[lane];
      acc.x += v.x; acc.y += v.y; acc.z += v.z; acc.w += v.w;
    }
    float vv[4] = {acc.x, acc.y, acc.z, acc.w};
    us4 hv, lv;
#pragma unroll
    for (int j = 0; j < 4; ++j) {
      unsigned short h = f2bf(vv[j]);
      hv[j] = h;
      lv[j] = f2bf(vv[j] - bf2f(h));
    }
    *(us4*)(HHi + (size_t)node * C + lane * 4) = hv;
    *(us4*)(HLo + (size_t)node * C + lane * 4) = lv;
  } else {  // C == 128
    float2 acc = ((const float2*)(X + (size_t)node * C))[lane];
    int e = e0;
    for (; e + 4 <= e1; e += 4) {
      int s0 = adj[e], s1 = adj[e + 1], s2 = adj[e + 2], s3 = adj[e + 3];
      float2 v0 = ((const float2*)(X + (size_t)s0 * C))[lane];
      float2 v1 = ((const float2*)(X + (size_t)s1 * C))[lane];
      float2 v2 = ((const float2*)(X + (size_t)s2 * C))[lane];
      float2 v3 = ((const float2*)(X + (size_t)s3 * C))[lane];
      acc.x += (v0.x + v1.x) + (v2.x + v3.x);
      acc.y += (v0.y + v1.y) + (v2.y + v3.y);
    }
    for (; e < e1; ++e) {
      int s = adj[e];
      float2 v = ((const float2*)(X + (size_t)s * C))[lane];
      acc.x += v.x; acc.y += v.y;
    }
    unsigned short hx = f2bf(acc.x), hy = f2bf(acc.y);
    ushort2 hv = {hx, hy};
    ushort2 lv = {f2bf(acc.x - bf2f(hx)), f2bf(acc.y - bf2f(hy))};
    *(ushort2*)(HHi + (size_t)node * C + lane * 2) = hv;
    *(ushort2*)(HLo + (size_t)node * C + lane * 2) = lv;
  }
}

// ---------------- MFMA GEMM: Out[M][Nld] = f(A[M][K]) @ W[K][Nout] + bias ----
// Split-bf16: acc += aHi*wHi + aHi*wLo + aLo*wHi  (~f32 accuracy).
// PRESPLIT: A arrives as hi/lo bf16 arrays (pure-copy staging, no VALU).
// BNP: A-load prologue relu(a*scale+shift) (f32 path only).
// EPI: 0 none, 1 relu, 2 tanh, 3 relu(tanh).
// STATS: epilogue accumulates per-column sum/sumsq of (acc+bias) into stats[].
template <bool PRESPLIT, bool BNP, int EPI, bool STATS>
__global__ __launch_bounds__(256) void k_gemm(const float* __restrict__ A,
                                              const unsigned short* __restrict__ AHi,
                                              const unsigned short* __restrict__ ALo,
                                              int M, int K, int Nld,
                                              const unsigned short* __restrict__ WHi,
                                              const unsigned short* __restrict__ WLo,
                                              const float* __restrict__ bias,
                                              const float* __restrict__ scsh,
                                              float* __restrict__ Out,
                                              float* __restrict__ stats) {
  __shared__ unsigned short aHi[128][56], aLo[128][56];  // pad 32->56: 16B rows
  __shared__ unsigned short bHi[128][56], bLo[128][56];
  const int tid = threadIdx.x;
  const int lane = tid & 63, w = tid >> 6;
  const int wm = w >> 1, wn = w & 1;
  const int m0 = blockIdx.x * 128;
  const int n0 = blockIdx.y * 128;

  f32x4 zero = {0.f, 0.f, 0.f, 0.f};
  f32x4 acc[4][4];
#pragma unroll
  for (int i = 0; i < 4; ++i)
#pragma unroll
    for (int j = 0; j < 4; ++j) acc[i][j] = zero;

  for (int kb = 0; kb < K; kb += 32) {
    __syncthreads();
    if constexpr (PRESPLIT) {
      // stage A tile: pure us8 copies from pre-split arrays (rows clamped; rows
      // >= M produce garbage only in output rows >= M, which are never stored)
#pragma unroll
      for (int q = 0; q < 2; ++q) {
        int idx = tid + q * 256;        // 8-elem chunk index, 512 total
        int nrow = idx >> 2, k8 = idx & 3;
        int grow = m0 + nrow; if (grow >= M) grow = M - 1;
        size_t go = (size_t)grow * K + kb + k8 * 8;
        *(us8*)&aHi[nrow][k8 * 8] = *(const us8*)(AHi + go);
        *(us8*)&aLo[nrow][k8 * 8] = *(const us8*)(ALo + go);
      }
    } else {
      // stage A tile 128x32 f32 -> bf16 hi/lo (optional BN+relu prologue)
#pragma unroll
      for (int q = 0; q < 4; ++q) {
        int idx = tid + q * 256;        // float4 index, 1024 total
        int row = idx >> 3, kq = idx & 7;
        int grow = m0 + row;
        float vv[4] = {0.f, 0.f, 0.f, 0.f};
        if (grow < M) {
          const float4 v = *(const float4*)(A + (size_t)grow * K + kb + kq * 4);
          vv[0] = v.x; vv[1] = v.y; vv[2] = v.z; vv[3] = v.w;
        }
        us4 hv, lv;
#pragma unroll
        for (int j = 0; j < 4; ++j) {
          float f = vv[j];
          if (BNP) {
            int kc = kb + kq * 4 + j;
            f = fmaxf(f * scsh[kc] + scsh[256 + kc], 0.f);
          }
          unsigned short h = f2bf(f);
          hv[j] = h;
          lv[j] = f2bf(f - bf2f(h));
        }
        *(us4*)&aHi[row][kq * 4] = hv;
        *(us4*)&aLo[row][kq * 4] = lv;
      }
    }
    // stage B tile: Wt rows [n0, n0+128) x 32 k, pre-split bf16
#pragma unroll
    for (int q = 0; q < 2; ++q) {
      int idx = tid + q * 256;          // 8-elem chunk index, 512 total
      int nrow = idx >> 2, k8 = idx & 3;
      size_t go = (size_t)(n0 + nrow) * K + kb + k8 * 8;
      *(us8*)&bHi[nrow][k8 * 8] = *(const us8*)(WHi + go);
      *(us8*)&bLo[nrow][k8 * 8] = *(const us8*)(WLo + go);
    }
    __syncthreads();

    const int ko = (lane >> 4) * 8;
    short8 bh[4], bl[4];
#pragma unroll
    for (int ni = 0; ni < 4; ++ni) {
      int r = wn * 64 + ni * 16 + (lane & 15);
      bh[ni] = *(const short8*)&bHi[r][ko];
      bl[ni] = *(const short8*)&bLo[r][ko];
    }
#pragma unroll
    for (int mi = 0; mi < 4; ++mi) {
      int r = wm * 64 + mi * 16 + (lane & 15);
      short8 ah = *(const short8*)&aHi[r][ko];
      short8 al = *(const short8*)&aLo[r][ko];
#pragma unroll
      for (int ni = 0; ni < 4; ++ni) {
        acc[mi][ni] = __builtin_amdgcn_mfma_f32_16x16x32_bf16(ah, bh[ni], acc[mi][ni], 0, 0, 0);
        acc[mi][ni] = __builtin_amdgcn_mfma_f32_16x16x32_bf16(ah, bl[ni], acc[mi][ni], 0, 0, 0);
        acc[mi][ni] = __builtin_amdgcn_mfma_f32_16x16x32_bf16(al, bh[ni], acc[mi][ni], 0, 0, 0);
      }
    }
  }

  // epilogue: C/D layout col = lane&15, row = (lane>>4)*4 + r   [m89-verified]
#pragma unroll
  for (int ni = 0; ni < 4; ++ni) {
    int col = n0 + wn * 64 + ni * 16 + (lane & 15);
    float bc = bias[col];
    float s = 0.f, q = 0.f;
#pragma unroll
    for (int mi = 0; mi < 4; ++mi) {
      int rbase = m0 + wm * 64 + mi * 16 + (lane >> 4) * 4;
#pragma unroll
      for (int r = 0; r < 4; ++r) {
        int row = rbase + r;
        if (row < M) {
          float o = acc[mi][ni][r] + bc;
          if (STATS) { s += o; q += o * o; }
          if (EPI == 1) o = fmaxf(o, 0.f);
          else if (EPI == 2) o = tanhf(o);
          else if (EPI == 3) o = fmaxf(tanhf(o), 0.f);
          Out[(size_t)row * Nld + col] = o;
        }
      }
    }
    if (STATS) {
      // reduce across the 4 lane-groups (lane>>4) holding the same column
      s += __shfl_xor(s, 16); s += __shfl_xor(s, 32);
      q += __shfl_xor(q, 16); q += __shfl_xor(q, 32);
      if ((lane >> 4) == 0) {
        atomicAdd(&stats[col], s);
        atomicAdd(&stats[256 + col], q);
      }
    }
  }
}

__global__ void k_finalize(const float* __restrict__ stats, const float* __restrict__ g,
                           const float* __restrict__ be, float* __restrict__ scsh, int M) {
  int c = threadIdx.x;
  float mu = stats[c] / (float)M;
  float var = stats[256 + c] / (float)M - mu * mu;
  float sc = g[c] * rsqrtf(var + 1e-5f);
  scsh[c] = sc;
  scsh[256 + c] = be[c] - mu * sc;
}

// ---------------- pooling ----------------
__global__ void k_bounds(const int* __restrict__ batch, int* __restrict__ gs,
                         int* __restrict__ ge, int N) {
  int i = blockIdx.x * 256 + threadIdx.x;
  if (i >= N) return;
  int b = batch[i];
  if (i == 0 || batch[i - 1] != b) gs[b] = i;
  if (i == N - 1 || batch[i + 1] != b) ge[b] = i + 1;
}

// 4 waves stride rows (4 gathers in flight), float4 lanes, LDS cross-wave sum.
__global__ __launch_bounds__(256) void k_pool(const float* __restrict__ Hf,
                                              const int* __restrict__ gs,
                                              const int* __restrict__ ge,
                                              float* __restrict__ pooled) {
  __shared__ float4 red[4][64];
  int g = blockIdx.x;
  int s = gs[g], e = ge[g];
  int w = threadIdx.x >> 6, lane = threadIdx.x & 63;
  float4 acc = {0.f, 0.f, 0.f, 0.f};
  for (int r = s + w; r < e; r += 4) {
    float4 v = ((const float4*)(Hf + (size_t)r * 256))[lane];
    acc.x += v.x; acc.y += v.y; acc.z += v.z; acc.w += v.w;
  }
  red[w][lane] = acc;
  __syncthreads();
  if (w == 0) {
    float4 a = red[0][lane], b = red[1][lane], c = red[2][lane], d = red[3][lane];
    float inv = 1.0f / fmaxf((float)(e - s), 1.0f);
    float4 o;
    o.x = (a.x + b.x + c.x + d.x) * inv;
    o.y = (a.y + b.y + c.y + d.y) * inv;
    o.z = (a.z + b.z + c.z + d.z) * inv;
    o.w = (a.w + b.w + c.w + d.w) * inv;
    ((float4*)(pooled + g * 256))[lane] = o;
  }
}

// ---------------------------------------------------------------------------
extern "C" void kernel_launch(void* const* d_in, const int* in_sizes, int n_in,
                              void* d_out, int out_size, void* d_ws, size_t ws_size,
                              hipStream_t stream) {
  const float* x      = (const float*)d_in[0];
  const int* ei       = (const int*)d_in[1];    // int32 from harness
  const int* bat      = (const int*)d_in[2];    // int32 from harness
  const float* w1a = (const float*)d_in[3];  const float* b1a = (const float*)d_in[4];
  const float* g1  = (const float*)d_in[5];  const float* be1 = (const float*)d_in[6];
  const float* w1b = (const float*)d_in[7];  const float* b1b = (const float*)d_in[8];
  const float* w2a = (const float*)d_in[9];  const float* b2a = (const float*)d_in[10];
  const float* g2  = (const float*)d_in[11]; const float* be2 = (const float*)d_in[12];
  const float* w2b = (const float*)d_in[13]; const float* b2b = (const float*)d_in[14];
  const float* w3a = (const float*)d_in[15]; const float* b3a = (const float*)d_in[16];
  const float* g3  = (const float*)d_in[17]; const float* be3 = (const float*)d_in[18];
  const float* w3b = (const float*)d_in[19]; const float* b3b = (const float*)d_in[20];
  const float* wh1 = (const float*)d_in[21]; const float* bh1 = (const float*)d_in[22];
  const float* wh2 = (const float*)d_in[23]; const float* bh2 = (const float*)d_in[24];
  float* out = (float*)d_out;

  const int N = in_sizes[0] / 128;   // 50000
  const int E = in_sizes[1] / 2;     // 800000
  const int G = 512;

  // ---- workspace layout (ping-pong: two 51MB regions swap roles) ----
  char* ws = (char*)d_ws;
  size_t off = 0;
  auto alloc = [&](size_t bytes) {
    void* p = ws + off;
    off = (off + bytes + 255) & ~(size_t)255;
    return p;
  };
  char* regP = (char*)alloc((size_t)N * 256 * 4);
  char* regQ = (char*)alloc((size_t)N * 256 * 4);
  int* adj     = (int*)alloc((size_t)E * 4);
  int* rowptr  = (int*)alloc((size_t)(N + 1) * 4);
  int* cursor  = (int*)alloc((size_t)N * 4);
  int* deg     = (int*)alloc((size_t)N * 4);
  unsigned short* wHi = (unsigned short*)alloc(884736 * 2);
  unsigned short* wLo = (unsigned short*)alloc(884736 * 2);
  float* stats = (float*)alloc(512 * 4);
  float* scsh  = (float*)alloc(512 * 4);
  int* gs      = (int*)alloc(G * 4);
  int* ge      = (int*)alloc(G * 4);
  float* pooled = (float*)alloc((size_t)G * 256 * 4);
  float* thid   = (float*)alloc((size_t)G * 512 * 4);

  // region views: f32 activation | split (hi at base, lo at base + N*256 us)
  float* Pf = (float*)regP;             float* Qf = (float*)regQ;
  unsigned short* Phi = (unsigned short*)regP;
  unsigned short* Plo = Phi + (size_t)N * 256;
  unsigned short* Qhi = (unsigned short*)regQ;
  unsigned short* Qlo = Qhi + (size_t)N * 256;

  // transposed-weight element offsets
  const int o1a = 0, o1b = 32768, o2a = 98304, o2b = 163840, o3a = 229376, o3b = 294912;
  const int oh1 = 360448, oh2 = 491520;   // ends at 884736

  hipMemsetAsync(deg, 0, (size_t)N * 4, stream);
  hipMemsetAsync(gs, 0, (size_t)G * 4, stream);
  hipMemsetAsync(ge, 0, (size_t)G * 4, stream);

  int eb = (E + 255) / 256;
  k_hist<<<eb, 256, 0, stream>>>(ei, deg, E);
  k_scan<<<1, 1024, 0, stream>>>(deg, rowptr, cursor, N);
  k_fill<<<eb, 256, 0, stream>>>(ei, cursor, adj, E);

  k_prep<<<128, 256, 0, stream>>>(w1a, wHi + o1a, wLo + o1a, 128, 256);
  k_prep<<<256, 256, 0, stream>>>(w1b, wHi + o1b, wLo + o1b, 256, 256);
  k_prep<<<256, 256, 0, stream>>>(w2a, wHi + o2a, wLo + o2a, 256, 256);
  k_prep<<<256, 256, 0, stream>>>(w2b, wHi + o2b, wLo + o2b, 256, 256);
  k_prep<<<256, 256, 0, stream>>>(w3a, wHi + o3a, wLo + o3a, 256, 256);
  k_prep<<<256, 256, 0, stream>>>(w3b, wHi + o3b, wLo + o3b, 256, 256);
  k_prep<<<512, 256, 0, stream>>>(wh1, wHi + oh1, wLo + oh1, 256, 512);
  k_prep<<<1536, 256, 0, stream>>>(wh2, wHi + oh2, wLo + oh2, 512, 768);

  k_bounds<<<(N + 255) / 256, 256, 0, stream>>>(bat, gs, ge, N);

  int nb4 = (N + 3) / 4;
  dim3 gg((N + 127) / 128, 2);

  // ---- layer 1: x ->split@Q ->z@P ->out@Q ----
  k_agg<128><<<nb4, 256, 0, stream>>>(x, Qhi, Qlo, rowptr, adj, N);
  hipMemsetAsync(stats, 0, 512 * 4, stream);
  k_gemm<true, false, 0, true><<<gg, 256, 0, stream>>>(nullptr, Qhi, Qlo, N, 128, 256, wHi + o1a, wLo + o1a, b1a, nullptr, Pf, stats);
  k_finalize<<<1, 256, 0, stream>>>(stats, g1, be1, scsh, N);
  k_gemm<false, true, 1, false><<<gg, 256, 0, stream>>>(Pf, nullptr, nullptr, N, 256, 256, wHi + o1b, wLo + o1b, b1b, scsh, Qf, nullptr);

  // ---- layer 2: Q ->split@P ->z@Q ->out@P ----
  k_agg<256><<<nb4, 256, 0, stream>>>(Qf, Phi, Plo, rowptr, adj, N);
  hipMemsetAsync(stats, 0, 512 * 4, stream);
  k_gemm<true, false, 0, true><<<gg, 256, 0, stream>>>(nullptr, Phi, Plo, N, 256, 256, wHi + o2a, wLo + o2a, b2a, nullptr, Qf, stats);
  k_finalize<<<1, 256, 0, stream>>>(stats, g2, be2, scsh, N);
  k_gemm<false, true, 3, false><<<gg, 256, 0, stream>>>(Qf, nullptr, nullptr, N, 256, 256, wHi + o2b, wLo + o2b, b2b, scsh, Pf, nullptr);

  // ---- layer 3: P ->split@Q ->z@P ->out@Q ----
  k_agg<256><<<nb4, 256, 0, stream>>>(Pf, Qhi, Qlo, rowptr, adj, N);
  hipMemsetAsync(stats, 0, 512 * 4, stream);
  k_gemm<true, false, 0, true><<<gg, 256, 0, stream>>>(nullptr, Qhi, Qlo, N, 256, 256, wHi + o3a, wLo + o3a, b3a, nullptr, Pf, stats);
  k_finalize<<<1, 256, 0, stream>>>(stats, g3, be3, scsh, N);
  k_gemm<false, true, 2, false><<<gg, 256, 0, stream>>>(Pf, nullptr, nullptr, N, 256, 256, wHi + o3b, wLo + o3b, b3b, scsh, Qf, nullptr);

  // ---- pool + MFMA heads ----
  k_pool<<<G, 256, 0, stream>>>(Qf, gs, ge, pooled);
  dim3 gh1(4, 4);   // M=512/128, N=512/128
  k_gemm<false, false, 1, false><<<gh1, 256, 0, stream>>>(pooled, nullptr, nullptr, G, 256, 512, wHi + oh1, wLo + oh1, bh1, nullptr, thid, nullptr);
  dim3 gh2(4, 6);   // M=512/128, N=768/128
  k_gemm<false, false, 0, false><<<gh2, 256, 0, stream>>>(thid, nullptr, nullptr, G, 512, 768, wHi + oh2, wLo + oh2, bh2, nullptr, out, nullptr);
}

// Round 6
// 943.425 us; speedup vs baseline: 1.3007x; 1.0678x over previous
//
#include <hip/hip_runtime.h>

// ---------------------------------------------------------------------------
// GIN GraphEncoder on MI355X.
// All GEMMs: MFMA split-bf16 (hi/lo, 3-product ~f32 accuracy), PRESPLIT
// operands staged global->LDS via global_load_lds(16B), T2-style swizzle:
// producers store 16B k-groups XOR-swizzled (g ^= row&7) so staging is linear
// and ds_read_b128 applies the same XOR (2-way conflicts = free).
// Per layer: agg (CSR gather, f32) -> split@Q -> gemmA (z@P f32 + fused BN
// stats) -> k_bn (BN+relu -> split@Q) -> gemmB (act@P f32 + epilogue).
// Then pool (split out) + 2 MFMA heads. Integer inputs arrive as int32.
// ---------------------------------------------------------------------------

typedef __attribute__((ext_vector_type(8))) short short8;   // 8 bf16 for MFMA
typedef __attribute__((ext_vector_type(4))) float f32x4;
typedef __attribute__((ext_vector_type(4))) unsigned short us4;
typedef __attribute__((ext_vector_type(8))) unsigned short us8;

__device__ __forceinline__ unsigned short f2bf(float f) {
  unsigned int b = __float_as_uint(f);
  unsigned int r = 0x7FFFu + ((b >> 16) & 1u);   // round-to-nearest-even
  return (unsigned short)((b + r) >> 16);
}
__device__ __forceinline__ float bf2f(unsigned short u) {
  return __uint_as_float(((unsigned int)u) << 16);
}

// global->LDS 16B async copy; LDS dest must be wave-uniform base (HW adds lane*16)
typedef const __attribute__((address_space(1))) unsigned int* gas1;
typedef __attribute__((address_space(3))) unsigned int* las3;
__device__ __forceinline__ void gload16(const void* g, void* l) {
  __builtin_amdgcn_global_load_lds((gas1)g, (las3)l, 16, 0, 0);
}

// swizzled flat index of element (row, k) in a presplit array with row length K:
// 16B groups (8 us) XORed within each 64-elem block: g' = g ^ (row&7)
__device__ __forceinline__ size_t swz_idx(int row, int k, int K) {
  int g = k >> 3;
  return (size_t)row * K + ((g >> 3) << 6) + ((((g & 7) ^ (row & 7)) << 3)) + (k & 7);
}

// ---------------- CSR build ----------------
__global__ void k_hist(const int* __restrict__ ei, int* __restrict__ deg, int E) {
  int e = blockIdx.x * 256 + threadIdx.x;
  if (e >= E) return;
  atomicAdd(&deg[ei[E + e]], 1);
}

__global__ __launch_bounds__(1024) void k_scan(const int* __restrict__ deg,
                                               int* __restrict__ rowptr,
                                               int* __restrict__ cursor, int N) {
  __shared__ int sd[1024];
  __shared__ int running;
  int tid = threadIdx.x;
  if (tid == 0) { running = 0; rowptr[0] = 0; }
  __syncthreads();
  int iters = (N + 1023) >> 10;
  for (int it = 0; it < iters; ++it) {
    int i = (it << 10) + tid;
    int v = (i < N) ? deg[i] : 0;
    sd[tid] = v;
    __syncthreads();
    for (int off = 1; off < 1024; off <<= 1) {
      int t = (tid >= off) ? sd[tid - off] : 0;
      __syncthreads();
      sd[tid] += t;
      __syncthreads();
    }
    int roff = running;
    int incl = sd[tid] + roff;
    if (i < N) { rowptr[i + 1] = incl; cursor[i] = incl - v; }
    __syncthreads();
    if (tid == 1023) running = incl;
    __syncthreads();
  }
}

__global__ void k_fill(const int* __restrict__ ei, int* __restrict__ cursor,
                       int* __restrict__ adj, int E) {
  int e = blockIdx.x * 256 + threadIdx.x;
  if (e >= E) return;
  int s = ei[e];
  int d = ei[E + e];
  int pos = atomicAdd(&cursor[d], 1);
  adj[pos] = s;
}

// ---- weight transpose + split + swizzle: W[K][Nout] -> Wt[n][k] swizzled ----
__global__ void k_prep(const float* __restrict__ W, unsigned short* __restrict__ Hi,
                       unsigned short* __restrict__ Lo, int K, int Nout) {
  int idx = blockIdx.x * 256 + threadIdx.x;
  if (idx >= K * Nout) return;
  int n = idx % Nout, k = idx / Nout;
  float w = W[k * Nout + n];
  unsigned short h = f2bf(w);
  size_t oi = swz_idx(n, k, K);
  Hi[oi] = h;
  Lo[oi] = f2bf(w - bf2f(h));
}

// -------- aggregation: h = X[i] + sum X[adj[e]]; write split+swizzled --------
template <int C>
__global__ __launch_bounds__(256) void k_agg(const float* __restrict__ X,
                                             unsigned short* __restrict__ HHi,
                                             unsigned short* __restrict__ HLo,
                                             const int* __restrict__ rowptr,
                                             const int* __restrict__ adj, int N) {
  int node = blockIdx.x * 4 + (threadIdx.x >> 6);
  if (node >= N) return;
  int lane = threadIdx.x & 63;
  int e0 = rowptr[node], e1 = rowptr[node + 1];
  if constexpr (C == 256) {
    float4 acc = ((const float4*)(X + (size_t)node * C))[lane];
    int e = e0;
    for (; e + 4 <= e1; e += 4) {
      int s0 = adj[e], s1 = adj[e + 1], s2 = adj[e + 2], s3 = adj[e + 3];
      float4 v0 = ((const float4*)(X + (size_t)s0 * C))[lane];
      float4 v1 = ((const float4*)(X + (size_t)s1 * C))[lane];
      float4 v2 = ((const float4*)(X + (size_t)s2 * C))[lane];
      float4 v3 = ((const float4*)(X + (size_t)s3 * C))[lane];
      acc.x += (v0.x + v1.x) + (v2.x + v3.x);
      acc.y += (v0.y + v1.y) + (v2.y + v3.y);
      acc.z += (v0.z + v1.z) + (v2.z + v3.z);
      acc.w += (v0.w + v1.w) + (v2.w + v3.w);
    }
    for (; e < e1; ++e) {
      int s = adj[e];
      float4 v = ((const float4*)(X + (size_t)s * C))[lane];
      acc.x += v.x; acc.y += v.y; acc.z += v.z; acc.w += v.w;
    }
    float vv[4] = {acc.x, acc.y, acc.z, acc.w};
    us4 hv, lv;
#pragma unroll
    for (int j = 0; j < 4; ++j) {
      unsigned short h = f2bf(vv[j]);
      hv[j] = h;
      lv[j] = f2bf(vv[j] - bf2f(h));
    }
    // lane covers cols lane*4..+3 -> group g = lane>>1, half = lane&1
    int g = lane >> 1;
    size_t oi = (size_t)node * 256 + ((g >> 3) << 6) +
                ((((g & 7) ^ (node & 7)) << 3)) + ((lane & 1) << 2);
    *(us4*)(HHi + oi) = hv;
    *(us4*)(HLo + oi) = lv;
  } else {  // C == 128
    float2 acc = ((const float2*)(X + (size_t)node * C))[lane];
    int e = e0;
    for (; e + 4 <= e1; e += 4) {
      int s0 = adj[e], s1 = adj[e + 1], s2 = adj[e + 2], s3 = adj[e + 3];
      float2 v0 = ((const float2*)(X + (size_t)s0 * C))[lane];
      float2 v1 = ((const float2*)(X + (size_t)s1 * C))[lane];
      float2 v2 = ((const float2*)(X + (size_t)s2 * C))[lane];
      float2 v3 = ((const float2*)(X + (size_t)s3 * C))[lane];
      acc.x += (v0.x + v1.x) + (v2.x + v3.x);
      acc.y += (v0.y + v1.y) + (v2.y + v3.y);
    }
    for (; e < e1; ++e) {
      int s = adj[e];
      float2 v = ((const float2*)(X + (size_t)s * C))[lane];
      acc.x += v.x; acc.y += v.y;
    }
    unsigned short hx = f2bf(acc.x), hy = f2bf(acc.y);
    ushort2 hv = {hx, hy};
    ushort2 lv = {f2bf(acc.x - bf2f(hx)), f2bf(acc.y - bf2f(hy))};
    // lane covers cols lane*2..+1 -> group g = lane>>2, quarter = lane&3
    int g = lane >> 2;
    size_t oi = (size_t)node * 128 + ((g >> 3) << 6) +
                ((((g & 7) ^ (node & 7)) << 3)) + ((lane & 3) << 1);
    *(ushort2*)(HHi + oi) = hv;
    *(ushort2*)(HLo + oi) = lv;
  }
}

// -------- BN+relu elementwise: z f32 -> split+swizzled bf16 hi/lo --------
__global__ __launch_bounds__(256) void k_bn(const float* __restrict__ Z,
                                            const float* __restrict__ scsh,
                                            unsigned short* __restrict__ OHi,
                                            unsigned short* __restrict__ OLo,
                                            int N) {
  int t = blockIdx.x * 256 + threadIdx.x;    // one 8-elem group per thread
  if (t >= N * 32) return;
  int row = t >> 5, g = t & 31;
  int k0 = g << 3;
  const float* zp = Z + (size_t)row * 256 + k0;
  float4 v0 = *(const float4*)zp;
  float4 v1 = *(const float4*)(zp + 4);
  float f[8] = {v0.x, v0.y, v0.z, v0.w, v1.x, v1.y, v1.z, v1.w};
  us8 hv, lv;
#pragma unroll
  for (int j = 0; j < 8; ++j) {
    float o = fmaxf(f[j] * scsh[k0 + j] + scsh[256 + k0 + j], 0.f);
    unsigned short h = f2bf(o);
    hv[j] = h;
    lv[j] = f2bf(o - bf2f(h));
  }
  size_t oi = (size_t)row * 256 + ((g >> 3) << 6) + ((((g & 7) ^ (row & 7)) << 3));
  *(us8*)(OHi + oi) = hv;
  *(us8*)(OLo + oi) = lv;
}

// ---------------- MFMA GEMM (m97-style staging) ----------------
// Out[M][Nld] = A[M][K] @ Wt^T + bias, A/W presplit+swizzled.
// BK=64; LDS linear; global_load_lds 16B; ds_read applies the XOR swizzle.
// EPI: 0 none, 1 relu, 2 tanh, 3 relu(tanh). STATS: fused BN sum/sumsq.
// OSPLIT: write split+swizzled (with relu), else f32.
template <int EPI, bool STATS, bool OSPLIT>
__global__ __launch_bounds__(256) void k_gemm(
    const unsigned short* __restrict__ AHi, const unsigned short* __restrict__ ALo,
    int M, int K, int Nld,
    const unsigned short* __restrict__ WHi, const unsigned short* __restrict__ WLo,
    const float* __restrict__ bias, float* __restrict__ Out,
    unsigned short* __restrict__ OHi, unsigned short* __restrict__ OLo,
    float* __restrict__ stats) {
  __shared__ unsigned short aHi[8192], aLo[8192], bHi[8192], bLo[8192];  // 4x16KB
  const int tid = threadIdx.x;
  const int lane = tid & 63, w = tid >> 6;
  const int wm = w >> 1, wn = w & 1;
  const int m0 = blockIdx.x * 128, n0 = blockIdx.y * 128;

  f32x4 zero = {0.f, 0.f, 0.f, 0.f};
  f32x4 acc[4][4];
#pragma unroll
  for (int i = 0; i < 4; ++i)
#pragma unroll
    for (int j = 0; j < 4; ++j) acc[i][j] = zero;

  // staging: wave w covers rows [32w,32w+32); issue q: rows 32w+8q..+7.
  // lane l -> row 32w+8q+(l>>3), k-group l&7; LDS linear (= l*16 off base).
  const int rq = (w << 5) + (lane >> 3);
  const int k8s = lane & 7;

  for (int kb = 0; kb < K; kb += 64) {
    __syncthreads();
#pragma unroll
    for (int q = 0; q < 4; ++q) {
      int ra = m0 + rq + q * 8; if (ra >= M) ra = M - 1;   // clamp tail (junk rows never stored)
      size_t ga = (size_t)ra * K + kb + k8s * 8;           // swizzles cancel -> linear
      int rb = n0 + rq + q * 8;
      size_t gb = (size_t)rb * K + kb + k8s * 8;
      unsigned bo = (w << 12) + (q << 10);                 // wave-uniform LDS base
      gload16(AHi + ga, (char*)aHi + bo);
      gload16(ALo + ga, (char*)aLo + bo);
      gload16(WHi + gb, (char*)bHi + bo);
      gload16(WLo + gb, (char*)bLo + bo);
    }
    __syncthreads();   // compiler drains vmcnt(0) before s_barrier -> LDS ready

#pragma unroll
    for (int kk = 0; kk < 2; ++kk) {
      short8 bh[4], bl[4];
#pragma unroll
      for (int ni = 0; ni < 4; ++ni) {
        int r = wn * 64 + ni * 16 + (lane & 15);
        int bo = r * 128 + ((((kk << 2) + (lane >> 4)) ^ (r & 7)) << 4);
        bh[ni] = *(const short8*)((const char*)bHi + bo);
        bl[ni] = *(const short8*)((const char*)bLo + bo);
      }
#pragma unroll
      for (int mi = 0; mi < 4; ++mi) {
        int r = wm * 64 + mi * 16 + (lane & 15);
        int bo = r * 128 + ((((kk << 2) + (lane >> 4)) ^ (r & 7)) << 4);
        short8 ah = *(const short8*)((const char*)aHi + bo);
        short8 al = *(const short8*)((const char*)aLo + bo);
#pragma unroll
        for (int ni = 0; ni < 4; ++ni) {
          acc[mi][ni] = __builtin_amdgcn_mfma_f32_16x16x32_bf16(ah, bh[ni], acc[mi][ni], 0, 0, 0);
          acc[mi][ni] = __builtin_amdgcn_mfma_f32_16x16x32_bf16(ah, bl[ni], acc[mi][ni], 0, 0, 0);
          acc[mi][ni] = __builtin_amdgcn_mfma_f32_16x16x32_bf16(al, bh[ni], acc[mi][ni], 0, 0, 0);
        }
      }
    }
  }

  // epilogue: C/D layout col = lane&15, row = (lane>>4)*4 + r   [m89-verified]
#pragma unroll
  for (int ni = 0; ni < 4; ++ni) {
    int col = n0 + wn * 64 + ni * 16 + (lane & 15);
    float bc = bias[col];
    float s = 0.f, q = 0.f;
#pragma unroll
    for (int mi = 0; mi < 4; ++mi) {
      int rbase = m0 + wm * 64 + mi * 16 + (lane >> 4) * 4;
#pragma unroll
      for (int r = 0; r < 4; ++r) {
        int row = rbase + r;
        if (row < M) {
          float o = acc[mi][ni][r] + bc;
          if (STATS) { s += o; q += o * o; }
          if (OSPLIT) {
            o = fmaxf(o, 0.f);   // relu (head1)
            unsigned short h = f2bf(o);
            size_t oi = swz_idx(row, col, Nld);
            OHi[oi] = h;
            OLo[oi] = f2bf(o - bf2f(h));
          } else {
            if (EPI == 1) o = fmaxf(o, 0.f);
            else if (EPI == 2) o = tanhf(o);
            else if (EPI == 3) o = fmaxf(tanhf(o), 0.f);
            Out[(size_t)row * Nld + col] = o;
          }
        }
      }
    }
    if (STATS) {
      s += __shfl_xor(s, 16); s += __shfl_xor(s, 32);
      q += __shfl_xor(q, 16); q += __shfl_xor(q, 32);
      if ((lane >> 4) == 0) {
        atomicAdd(&stats[col], s);
        atomicAdd(&stats[256 + col], q);
      }
    }
  }
}

__global__ void k_finalize(const float* __restrict__ stats, const float* __restrict__ g,
                           const float* __restrict__ be, float* __restrict__ scsh, int M) {
  int c = threadIdx.x;
  float mu = stats[c] / (float)M;
  float var = stats[256 + c] / (float)M - mu * mu;
  float sc = g[c] * rsqrtf(var + 1e-5f);
  scsh[c] = sc;
  scsh[256 + c] = be[c] - mu * sc;
}

// ---------------- pooling ----------------
__global__ void k_bounds(const int* __restrict__ batch, int* __restrict__ gs,
                         int* __restrict__ ge, int N) {
  int i = blockIdx.x * 256 + threadIdx.x;
  if (i >= N) return;
  int b = batch[i];
  if (i == 0 || batch[i - 1] != b) gs[b] = i;
  if (i == N - 1 || batch[i + 1] != b) ge[b] = i + 1;
}

// 4 waves stride rows, float4 lanes, LDS reduce; write split+swizzled.
__global__ __launch_bounds__(256) void k_pool(const float* __restrict__ Hf,
                                              const int* __restrict__ gs,
                                              const int* __restrict__ ge,
                                              unsigned short* __restrict__ PHi,
                                              unsigned short* __restrict__ PLo) {
  __shared__ float4 red[4][64];
  int gi = blockIdx.x;
  int s = gs[gi], e = ge[gi];
  int w = threadIdx.x >> 6, lane = threadIdx.x & 63;
  float4 acc = {0.f, 0.f, 0.f, 0.f};
  for (int r = s + w; r < e; r += 4) {
    float4 v = ((const float4*)(Hf + (size_t)r * 256))[lane];
    acc.x += v.x; acc.y += v.y; acc.z += v.z; acc.w += v.w;
  }
  red[w][lane] = acc;
  __syncthreads();
  if (w == 0) {
    float4 a = red[0][lane], b = red[1][lane], c = red[2][lane], d = red[3][lane];
    float inv = 1.0f / fmaxf((float)(e - s), 1.0f);
    float vv[4] = {(a.x + b.x + c.x + d.x) * inv, (a.y + b.y + c.y + d.y) * inv,
                   (a.z + b.z + c.z + d.z) * inv, (a.w + b.w + c.w + d.w) * inv};
    us4 hv, lv;
#pragma unroll
    for (int j = 0; j < 4; ++j) {
      unsigned short h = f2bf(vv[j]);
      hv[j] = h;
      lv[j] = f2bf(vv[j] - bf2f(h));
    }
    int g = lane >> 1;
    size_t oi = (size_t)gi * 256 + ((g >> 3) << 6) +
                ((((g & 7) ^ (gi & 7)) << 3)) + ((lane & 1) << 2);
    *(us4*)(PHi + oi) = hv;
    *(us4*)(PLo + oi) = lv;
  }
}

// ---------------------------------------------------------------------------
extern "C" void kernel_launch(void* const* d_in, const int* in_sizes, int n_in,
                              void* d_out, int out_size, void* d_ws, size_t ws_size,
                              hipStream_t stream) {
  const float* x      = (const float*)d_in[0];
  const int* ei       = (const int*)d_in[1];    // int32 from harness
  const int* bat      = (const int*)d_in[2];    // int32 from harness
  const float* w1a = (const float*)d_in[3];  const float* b1a = (const float*)d_in[4];
  const float* g1  = (const float*)d_in[5];  const float* be1 = (const float*)d_in[6];
  const float* w1b = (const float*)d_in[7];  const float* b1b = (const float*)d_in[8];
  const float* w2a = (const float*)d_in[9];  const float* b2a = (const float*)d_in[10];
  const float* g2  = (const float*)d_in[11]; const float* be2 = (const float*)d_in[12];
  const float* w2b = (const float*)d_in[13]; const float* b2b = (const float*)d_in[14];
  const float* w3a = (const float*)d_in[15]; const float* b3a = (const float*)d_in[16];
  const float* g3  = (const float*)d_in[17]; const float* be3 = (const float*)d_in[18];
  const float* w3b = (const float*)d_in[19]; const float* b3b = (const float*)d_in[20];
  const float* wh1 = (const float*)d_in[21]; const float* bh1 = (const float*)d_in[22];
  const float* wh2 = (const float*)d_in[23]; const float* bh2 = (const float*)d_in[24];
  float* out = (float*)d_out;

  const int N = in_sizes[0] / 128;   // 50000
  const int E = in_sizes[1] / 2;     // 800000
  const int G = 512;

  // ---- workspace layout: P = f32 region (z / act), Q = split region ----
  char* ws = (char*)d_ws;
  size_t off = 0;
  auto alloc = [&](size_t bytes) {
    void* p = ws + off;
    off = (off + bytes + 255) & ~(size_t)255;
    return p;
  };
  float* Pf = (float*)alloc((size_t)N * 256 * 4);
  unsigned short* Qhi = (unsigned short*)alloc((size_t)N * 256 * 2);
  unsigned short* Qlo = (unsigned short*)alloc((size_t)N * 256 * 2);
  int* adj     = (int*)alloc((size_t)E * 4);
  int* rowptr  = (int*)alloc((size_t)(N + 1) * 4);
  int* cursor  = (int*)alloc((size_t)N * 4);
  int* deg     = (int*)alloc((size_t)N * 4);
  unsigned short* wHi = (unsigned short*)alloc(884736 * 2);
  unsigned short* wLo = (unsigned short*)alloc(884736 * 2);
  float* stats = (float*)alloc(512 * 4);
  float* scsh  = (float*)alloc(512 * 4);
  int* gs      = (int*)alloc(G * 4);
  int* ge      = (int*)alloc(G * 4);
  unsigned short* poolHi = (unsigned short*)alloc((size_t)G * 256 * 2);
  unsigned short* poolLo = (unsigned short*)alloc((size_t)G * 256 * 2);
  unsigned short* thidHi = (unsigned short*)alloc((size_t)G * 512 * 2);
  unsigned short* thidLo = (unsigned short*)alloc((size_t)G * 512 * 2);

  // transposed-weight element offsets
  const int o1a = 0, o1b = 32768, o2a = 98304, o2b = 163840, o3a = 229376, o3b = 294912;
  const int oh1 = 360448, oh2 = 491520;   // ends at 884736

  hipMemsetAsync(deg, 0, (size_t)N * 4, stream);
  hipMemsetAsync(gs, 0, (size_t)G * 4, stream);
  hipMemsetAsync(ge, 0, (size_t)G * 4, stream);

  int eb = (E + 255) / 256;
  k_hist<<<eb, 256, 0, stream>>>(ei, deg, E);
  k_scan<<<1, 1024, 0, stream>>>(deg, rowptr, cursor, N);
  k_fill<<<eb, 256, 0, stream>>>(ei, cursor, adj, E);

  k_prep<<<128, 256, 0, stream>>>(w1a, wHi + o1a, wLo + o1a, 128, 256);
  k_prep<<<256, 256, 0, stream>>>(w1b, wHi + o1b, wLo + o1b, 256, 256);
  k_prep<<<256, 256, 0, stream>>>(w2a, wHi + o2a, wLo + o2a, 256, 256);
  k_prep<<<256, 256, 0, stream>>>(w2b, wHi + o2b, wLo + o2b, 256, 256);
  k_prep<<<256, 256, 0, stream>>>(w3a, wHi + o3a, wLo + o3a, 256, 256);
  k_prep<<<256, 256, 0, stream>>>(w3b, wHi + o3b, wLo + o3b, 256, 256);
  k_prep<<<512, 256, 0, stream>>>(wh1, wHi + oh1, wLo + oh1, 256, 512);
  k_prep<<<1536, 256, 0, stream>>>(wh2, wHi + oh2, wLo + oh2, 512, 768);

  k_bounds<<<(N + 255) / 256, 256, 0, stream>>>(bat, gs, ge, N);

  int nb4 = (N + 3) / 4;
  int bnb = (N * 32 + 255) / 256;
  dim3 gg((N + 127) / 128, 2);

  // ---- layer 1 ----
  k_agg<128><<<nb4, 256, 0, stream>>>(x, Qhi, Qlo, rowptr, adj, N);
  hipMemsetAsync(stats, 0, 512 * 4, stream);
  k_gemm<0, true, false><<<gg, 256, 0, stream>>>(Qhi, Qlo, N, 128, 256, wHi + o1a, wLo + o1a, b1a, Pf, nullptr, nullptr, stats);
  k_finalize<<<1, 256, 0, stream>>>(stats, g1, be1, scsh, N);
  k_bn<<<bnb, 256, 0, stream>>>(Pf, scsh, Qhi, Qlo, N);
  k_gemm<1, false, false><<<gg, 256, 0, stream>>>(Qhi, Qlo, N, 256, 256, wHi + o1b, wLo + o1b, b1b, Pf, nullptr, nullptr, nullptr);

  // ---- layer 2 ----
  k_agg<256><<<nb4, 256, 0, stream>>>(Pf, Qhi, Qlo, rowptr, adj, N);
  hipMemsetAsync(stats, 0, 512 * 4, stream);
  k_gemm<0, true, false><<<gg, 256, 0, stream>>>(Qhi, Qlo, N, 256, 256, wHi + o2a, wLo + o2a, b2a, Pf, nullptr, nullptr, stats);
  k_finalize<<<1, 256, 0, stream>>>(stats, g2, be2, scsh, N);
  k_bn<<<bnb, 256, 0, stream>>>(Pf, scsh, Qhi, Qlo, N);
  k_gemm<3, false, false><<<gg, 256, 0, stream>>>(Qhi, Qlo, N, 256, 256, wHi + o2b, wLo + o2b, b2b, Pf, nullptr, nullptr, nullptr);

  // ---- layer 3 ----
  k_agg<256><<<nb4, 256, 0, stream>>>(Pf, Qhi, Qlo, rowptr, adj, N);
  hipMemsetAsync(stats, 0, 512 * 4, stream);
  k_gemm<0, true, false><<<gg, 256, 0, stream>>>(Qhi, Qlo, N, 256, 256, wHi + o3a, wLo + o3a, b3a, Pf, nullptr, nullptr, stats);
  k_finalize<<<1, 256, 0, stream>>>(stats, g3, be3, scsh, N);
  k_bn<<<bnb, 256, 0, stream>>>(Pf, scsh, Qhi, Qlo, N);
  k_gemm<2, false, false><<<gg, 256, 0, stream>>>(Qhi, Qlo, N, 256, 256, wHi + o3b, wLo + o3b, b3b, Pf, nullptr, nullptr, nullptr);

  // ---- pool + MFMA heads ----
  k_pool<<<G, 256, 0, stream>>>(Pf, gs, ge, poolHi, poolLo);
  dim3 gh1(4, 4);   // M=512/128, N=512/128
  k_gemm<1, false, true><<<gh1, 256, 0, stream>>>(poolHi, poolLo, G, 256, 512, wHi + oh1, wLo + oh1, bh1, nullptr, thidHi, thidLo, nullptr);
  dim3 gh2(4, 6);   // M=512/128, N=768/128
  k_gemm<0, false, false><<<gh2, 256, 0, stream>>>(thidHi, thidLo, G, 512, 768, wHi + oh2, wLo + oh2, bh2, out, nullptr, nullptr, nullptr);
}

// Round 7
// 873.853 us; speedup vs baseline: 1.4042x; 1.0796x over previous
//
#include <hip/hip_runtime.h>

// ---------------------------------------------------------------------------
// GIN GraphEncoder on MI355X.
// All GEMMs: MFMA split-bf16 (hi/lo, 3-product ~f32 accuracy), PRESPLIT
// operands staged global->LDS via global_load_lds(16B). BK=32 (32KB LDS ->
// 4-5 blocks/CU, m97 regime). Storage swizzle: 16B k-groups XORed within
// 32-elem blocks (g' = g ^ (row&3)) so staging is linear and ds_read_b128
// applies the same XOR. Main GEMMs use XCD-pair swizzle (both N-halves of an
// M-tile on the same XCD -> A read once per XCD L2).
// Per layer: agg (CSR gather f32 -> split) -> gemmA (z f32 + fused BN stats)
// -> k_bn (BN+relu -> split) -> gemmB (+epilogue). Pool + 2 MFMA heads.
// Integer inputs arrive as int32. CSR scan is 3-phase parallel.
// ---------------------------------------------------------------------------

typedef __attribute__((ext_vector_type(8))) short short8;   // 8 bf16 for MFMA
typedef __attribute__((ext_vector_type(4))) float f32x4;
typedef __attribute__((ext_vector_type(4))) unsigned short us4;
typedef __attribute__((ext_vector_type(8))) unsigned short us8;

__device__ __forceinline__ unsigned short f2bf(float f) {
  unsigned int b = __float_as_uint(f);
  unsigned int r = 0x7FFFu + ((b >> 16) & 1u);   // round-to-nearest-even
  return (unsigned short)((b + r) >> 16);
}
__device__ __forceinline__ float bf2f(unsigned short u) {
  return __uint_as_float(((unsigned int)u) << 16);
}

// global->LDS 16B async copy; LDS dest is wave-uniform base (HW adds lane*16)
typedef const __attribute__((address_space(1))) unsigned int* gas1;
typedef __attribute__((address_space(3))) unsigned int* las3;
__device__ __forceinline__ void gload16(const void* g, void* l) {
  __builtin_amdgcn_global_load_lds((gas1)g, (las3)l, 16, 0, 0);
}

// swizzled flat index of element (row, k), row length K:
// 16B groups (8 us) XORed within each 32-elem block: g' = g ^ (row&3)
__device__ __forceinline__ size_t swz4_idx(int row, int k, int K) {
  int g = k >> 3;
  return (size_t)row * K + ((g >> 2) << 5) + ((((g & 3) ^ (row & 3)) << 3)) + (k & 7);
}

// ---------------- CSR build ----------------
__global__ void k_hist(const int* __restrict__ ei, int* __restrict__ deg, int E) {
  int e = blockIdx.x * 256 + threadIdx.x;
  if (e >= E) return;
  atomicAdd(&deg[ei[E + e]], 1);
}

// phase 1: per-block (1024 elems) inclusive scan + block sum
__global__ __launch_bounds__(1024) void k_scan1(const int* __restrict__ deg,
                                                int* __restrict__ partial,
                                                int* __restrict__ bsum, int N) {
  __shared__ int sd[1024];
  int tid = threadIdx.x;
  int i = blockIdx.x * 1024 + tid;
  int v = (i < N) ? deg[i] : 0;
  sd[tid] = v;
  __syncthreads();
  for (int off = 1; off < 1024; off <<= 1) {
    int t = (tid >= off) ? sd[tid - off] : 0;
    __syncthreads();
    sd[tid] += t;
    __syncthreads();
  }
  if (i < N) partial[i] = sd[tid];
  if (tid == 1023) bsum[blockIdx.x] = sd[1023];
}

// phase 2: exclusive scan of <=64 block sums in one wave
__global__ void k_scan2(int* __restrict__ bsum, int nb) {
  int l = threadIdx.x;
  int orig = (l < nb) ? bsum[l] : 0;
  int v = orig;
  for (int off = 1; off < 64; off <<= 1) {
    int t = __shfl_up(v, off);
    if (l >= off) v += t;
  }
  if (l < nb) bsum[l] = v - orig;
}

// phase 3: rowptr / cursor
__global__ void k_scan3(const int* __restrict__ deg, const int* __restrict__ partial,
                        const int* __restrict__ bsum, int* __restrict__ rowptr,
                        int* __restrict__ cursor, int N) {
  int i = blockIdx.x * 256 + threadIdx.x;
  if (i >= N) return;
  int incl = partial[i] + bsum[i >> 10];
  rowptr[i + 1] = incl;
  cursor[i] = incl - deg[i];
  if (i == 0) rowptr[0] = 0;
}

__global__ void k_fill(const int* __restrict__ ei, int* __restrict__ cursor,
                       int* __restrict__ adj, int E) {
  int e = blockIdx.x * 256 + threadIdx.x;
  if (e >= E) return;
  int s = ei[e];
  int d = ei[E + e];
  int pos = atomicAdd(&cursor[d], 1);
  adj[pos] = s;
}

// ---- weight transpose + split + swizzle: W[K][Nout] -> Wt[n][k] swizzled ----
__global__ void k_prep(const float* __restrict__ W, unsigned short* __restrict__ Hi,
                       unsigned short* __restrict__ Lo, int K, int Nout) {
  int idx = blockIdx.x * 256 + threadIdx.x;
  if (idx >= K * Nout) return;
  int n = idx % Nout, k = idx / Nout;
  float w = W[k * Nout + n];
  unsigned short h = f2bf(w);
  size_t oi = swz4_idx(n, k, K);
  Hi[oi] = h;
  Lo[oi] = f2bf(w - bf2f(h));
}

// -------- aggregation: h = X[i] + sum X[adj[e]]; write split+swizzled --------
template <int C>
__global__ __launch_bounds__(256) void k_agg(const float* __restrict__ X,
                                             unsigned short* __restrict__ HHi,
                                             unsigned short* __restrict__ HLo,
                                             const int* __restrict__ rowptr,
                                             const int* __restrict__ adj, int N) {
  int node = blockIdx.x * 4 + (threadIdx.x >> 6);
  if (node >= N) return;
  int lane = threadIdx.x & 63;
  int e0 = rowptr[node], e1 = rowptr[node + 1];
  if constexpr (C == 256) {
    float4 acc = ((const float4*)(X + (size_t)node * C))[lane];
    int e = e0;
    for (; e + 4 <= e1; e += 4) {
      int s0 = adj[e], s1 = adj[e + 1], s2 = adj[e + 2], s3 = adj[e + 3];
      float4 v0 = ((const float4*)(X + (size_t)s0 * C))[lane];
      float4 v1 = ((const float4*)(X + (size_t)s1 * C))[lane];
      float4 v2 = ((const float4*)(X + (size_t)s2 * C))[lane];
      float4 v3 = ((const float4*)(X + (size_t)s3 * C))[lane];
      acc.x += (v0.x + v1.x) + (v2.x + v3.x);
      acc.y += (v0.y + v1.y) + (v2.y + v3.y);
      acc.z += (v0.z + v1.z) + (v2.z + v3.z);
      acc.w += (v0.w + v1.w) + (v2.w + v3.w);
    }
    for (; e < e1; ++e) {
      int s = adj[e];
      float4 v = ((const float4*)(X + (size_t)s * C))[lane];
      acc.x += v.x; acc.y += v.y; acc.z += v.z; acc.w += v.w;
    }
    float vv[4] = {acc.x, acc.y, acc.z, acc.w};
    us4 hv, lv;
#pragma unroll
    for (int j = 0; j < 4; ++j) {
      unsigned short h = f2bf(vv[j]);
      hv[j] = h;
      lv[j] = f2bf(vv[j] - bf2f(h));
    }
    // lane covers cols lane*4..+3 -> group g = lane>>1, half = lane&1
    size_t oi = (size_t)node * 256 + ((lane >> 3) << 5) +
                ((((lane >> 1) & 3) ^ (node & 3)) << 3) + ((lane & 1) << 2);
    *(us4*)(HHi + oi) = hv;
    *(us4*)(HLo + oi) = lv;
  } else {  // C == 128
    float2 acc = ((const float2*)(X + (size_t)node * C))[lane];
    int e = e0;
    for (; e + 4 <= e1; e += 4) {
      int s0 = adj[e], s1 = adj[e + 1], s2 = adj[e + 2], s3 = adj[e + 3];
      float2 v0 = ((const float2*)(X + (size_t)s0 * C))[lane];
      float2 v1 = ((const float2*)(X + (size_t)s1 * C))[lane];
      float2 v2 = ((const float2*)(X + (size_t)s2 * C))[lane];
      float2 v3 = ((const float2*)(X + (size_t)s3 * C))[lane];
      acc.x += (v0.x + v1.x) + (v2.x + v3.x);
      acc.y += (v0.y + v1.y) + (v2.y + v3.y);
    }
    for (; e < e1; ++e) {
      int s = adj[e];
      float2 v = ((const float2*)(X + (size_t)s * C))[lane];
      acc.x += v.x; acc.y += v.y;
    }
    unsigned short hx = f2bf(acc.x), hy = f2bf(acc.y);
    ushort2 hv = {hx, hy};
    ushort2 lv = {f2bf(acc.x - bf2f(hx)), f2bf(acc.y - bf2f(hy))};
    // lane covers cols lane*2..+1 -> group g = lane>>2, quarter = lane&3
    size_t oi = (size_t)node * 128 + ((lane >> 4) << 5) +
                ((((lane >> 2) & 3) ^ (node & 3)) << 3) + ((lane & 3) << 1);
    *(ushort2*)(HHi + oi) = hv;
    *(ushort2*)(HLo + oi) = lv;
  }
}

// -------- BN+relu elementwise: z f32 -> split+swizzled bf16 hi/lo --------
__global__ __launch_bounds__(256) void k_bn(const float* __restrict__ Z,
                                            const float* __restrict__ scsh,
                                            unsigned short* __restrict__ OHi,
                                            unsigned short* __restrict__ OLo,
                                            int N) {
  int t = blockIdx.x * 256 + threadIdx.x;    // one 8-elem group per thread
  if (t >= N * 32) return;
  int row = t >> 5, g = t & 31;
  int k0 = g << 3;
  const float* zp = Z + (size_t)row * 256 + k0;
  float4 v0 = *(const float4*)zp;
  float4 v1 = *(const float4*)(zp + 4);
  float f[8] = {v0.x, v0.y, v0.z, v0.w, v1.x, v1.y, v1.z, v1.w};
  us8 hv, lv;
#pragma unroll
  for (int j = 0; j < 8; ++j) {
    float o = fmaxf(f[j] * scsh[k0 + j] + scsh[256 + k0 + j], 0.f);
    unsigned short h = f2bf(o);
    hv[j] = h;
    lv[j] = f2bf(o - bf2f(h));
  }
  size_t oi = (size_t)row * 256 + ((g >> 2) << 5) + (((g & 3) ^ (row & 3)) << 3);
  *(us8*)(OHi + oi) = hv;
  *(us8*)(OLo + oi) = lv;
}

// ---------------- MFMA GEMM (m97-style, BK=32, 32KB LDS) ----------------
// Out[M][Nld] = A[M][K] @ Wt^T + bias, A/W presplit+swizzled.
// EPI: 0 none, 1 relu, 2 tanh, 3 relu(tanh). STATS: fused BN sum/sumsq.
// OSPLIT: write split+swizzled (with relu). XSWZ: XCD-pair block swizzle
// (flat grid per*16; pairs (bx, by=0/1) adjacent on one XCD for A L2-reuse).
template <int EPI, bool STATS, bool OSPLIT, bool XSWZ>
__global__ __launch_bounds__(256) void k_gemm(
    const unsigned short* __restrict__ AHi, const unsigned short* __restrict__ ALo,
    int M, int K, int Nld, int mb, int per,
    const unsigned short* __restrict__ WHi, const unsigned short* __restrict__ WLo,
    const float* __restrict__ bias, float* __restrict__ Out,
    unsigned short* __restrict__ OHi, unsigned short* __restrict__ OLo,
    float* __restrict__ stats) {
  __shared__ unsigned short aHi[4096], aLo[4096], bHi[4096], bLo[4096];  // 4x8KB
  int bx, by;
  if constexpr (XSWZ) {
    int xcd = blockIdx.x & 7, slot = blockIdx.x >> 3;
    bx = xcd * per + (slot >> 1);
    by = slot & 1;
    if (bx >= mb) return;
  } else {
    bx = blockIdx.x;
    by = blockIdx.y;
  }
  const int tid = threadIdx.x;
  const int lane = tid & 63, w = tid >> 6;
  const int wm = w >> 1, wn = w & 1;
  const int m0 = bx * 128, n0 = by * 128;

  f32x4 zero = {0.f, 0.f, 0.f, 0.f};
  f32x4 acc[4][4];
#pragma unroll
  for (int i = 0; i < 4; ++i)
#pragma unroll
    for (int j = 0; j < 4; ++j) acc[i][j] = zero;

  // staging: wave w rows [32w,32w+32); issue q: rows 32w+16q+(lane>>2),
  // slot lane&3; LDS linear (lane*16 off wave-uniform base).
  const int rq = lane >> 2;
  const int k8s = lane & 3;

  for (int kb = 0; kb < K; kb += 32) {
    __syncthreads();
#pragma unroll
    for (int q = 0; q < 2; ++q) {
      int rloc = (w << 5) + (q << 4) + rq;
      int ra = m0 + rloc; if (ra >= M) ra = M - 1;   // clamp tail (junk never stored)
      size_t ga = (size_t)ra * K + kb + k8s * 8;     // swizzles cancel -> linear
      size_t gb = (size_t)(n0 + rloc) * K + kb + k8s * 8;
      unsigned bo = (w << 11) + (q << 10);           // wave-uniform LDS base
      gload16(AHi + ga, (char*)aHi + bo);
      gload16(ALo + ga, (char*)aLo + bo);
      gload16(WHi + gb, (char*)bHi + bo);
      gload16(WLo + gb, (char*)bLo + bo);
    }
    __syncthreads();   // compiler drains vmcnt(0) before s_barrier -> LDS ready

    const int j = lane >> 4;
    short8 bh[4], bl[4];
#pragma unroll
    for (int ni = 0; ni < 4; ++ni) {
      int r = wn * 64 + ni * 16 + (lane & 15);
      int bo = r * 64 + ((j ^ (r & 3)) << 4);
      bh[ni] = *(const short8*)((const char*)bHi + bo);
      bl[ni] = *(const short8*)((const char*)bLo + bo);
    }
#pragma unroll
    for (int mi = 0; mi < 4; ++mi) {
      int r = wm * 64 + mi * 16 + (lane & 15);
      int bo = r * 64 + ((j ^ (r & 3)) << 4);
      short8 ah = *(const short8*)((const char*)aHi + bo);
      short8 al = *(const short8*)((const char*)aLo + bo);
#pragma unroll
      for (int ni = 0; ni < 4; ++ni) {
        acc[mi][ni] = __builtin_amdgcn_mfma_f32_16x16x32_bf16(ah, bh[ni], acc[mi][ni], 0, 0, 0);
        acc[mi][ni] = __builtin_amdgcn_mfma_f32_16x16x32_bf16(ah, bl[ni], acc[mi][ni], 0, 0, 0);
        acc[mi][ni] = __builtin_amdgcn_mfma_f32_16x16x32_bf16(al, bh[ni], acc[mi][ni], 0, 0, 0);
      }
    }
  }

  // epilogue: C/D layout col = lane&15, row = (lane>>4)*4 + r   [m89-verified]
#pragma unroll
  for (int ni = 0; ni < 4; ++ni) {
    int col = n0 + wn * 64 + ni * 16 + (lane & 15);
    float bc = bias[col];
    float s = 0.f, q = 0.f;
#pragma unroll
    for (int mi = 0; mi < 4; ++mi) {
      int rbase = m0 + wm * 64 + mi * 16 + (lane >> 4) * 4;
#pragma unroll
      for (int r = 0; r < 4; ++r) {
        int row = rbase + r;
        if (row < M) {
          float o = acc[mi][ni][r] + bc;
          if (STATS) { s += o; q += o * o; }
          if (OSPLIT) {
            o = fmaxf(o, 0.f);   // relu (head1)
            unsigned short h = f2bf(o);
            size_t oi = swz4_idx(row, col, Nld);
            OHi[oi] = h;
            OLo[oi] = f2bf(o - bf2f(h));
          } else {
            if (EPI == 1) o = fmaxf(o, 0.f);
            else if (EPI == 2) o = tanhf(o);
            else if (EPI == 3) o = fmaxf(tanhf(o), 0.f);
            Out[(size_t)row * Nld + col] = o;
          }
        }
      }
    }
    if (STATS) {
      s += __shfl_xor(s, 16); s += __shfl_xor(s, 32);
      q += __shfl_xor(q, 16); q += __shfl_xor(q, 32);
      if ((lane >> 4) == 0) {
        atomicAdd(&stats[col], s);
        atomicAdd(&stats[256 + col], q);
      }
    }
  }
}

__global__ void k_finalize(const float* __restrict__ stats, const float* __restrict__ g,
                           const float* __restrict__ be, float* __restrict__ scsh, int M) {
  int c = threadIdx.x;
  float mu = stats[c] / (float)M;
  float var = stats[256 + c] / (float)M - mu * mu;
  float sc = g[c] * rsqrtf(var + 1e-5f);
  scsh[c] = sc;
  scsh[256 + c] = be[c] - mu * sc;
}

// ---------------- pooling ----------------
__global__ void k_bounds(const int* __restrict__ batch, int* __restrict__ gs,
                         int* __restrict__ ge, int N) {
  int i = blockIdx.x * 256 + threadIdx.x;
  if (i >= N) return;
  int b = batch[i];
  if (i == 0 || batch[i - 1] != b) gs[b] = i;
  if (i == N - 1 || batch[i + 1] != b) ge[b] = i + 1;
}

// 4 waves stride rows, float4 lanes, LDS reduce; write split+swizzled.
__global__ __launch_bounds__(256) void k_pool(const float* __restrict__ Hf,
                                              const int* __restrict__ gs,
                                              const int* __restrict__ ge,
                                              unsigned short* __restrict__ PHi,
                                              unsigned short* __restrict__ PLo) {
  __shared__ float4 red[4][64];
  int gi = blockIdx.x;
  int s = gs[gi], e = ge[gi];
  int w = threadIdx.x >> 6, lane = threadIdx.x & 63;
  float4 acc = {0.f, 0.f, 0.f, 0.f};
  for (int r = s + w; r < e; r += 4) {
    float4 v = ((const float4*)(Hf + (size_t)r * 256))[lane];
    acc.x += v.x; acc.y += v.y; acc.z += v.z; acc.w += v.w;
  }
  red[w][lane] = acc;
  __syncthreads();
  if (w == 0) {
    float4 a = red[0][lane], b = red[1][lane], c = red[2][lane], d = red[3][lane];
    float inv = 1.0f / fmaxf((float)(e - s), 1.0f);
    float vv[4] = {(a.x + b.x + c.x + d.x) * inv, (a.y + b.y + c.y + d.y) * inv,
                   (a.z + b.z + c.z + d.z) * inv, (a.w + b.w + c.w + d.w) * inv};
    us4 hv, lv;
#pragma unroll
    for (int j = 0; j < 4; ++j) {
      unsigned short h = f2bf(vv[j]);
      hv[j] = h;
      lv[j] = f2bf(vv[j] - bf2f(h));
    }
    size_t oi = (size_t)gi * 256 + ((lane >> 3) << 5) +
                ((((lane >> 1) & 3) ^ (gi & 3)) << 3) + ((lane & 1) << 2);
    *(us4*)(PHi + oi) = hv;
    *(us4*)(PLo + oi) = lv;
  }
}

// ---------------------------------------------------------------------------
extern "C" void kernel_launch(void* const* d_in, const int* in_sizes, int n_in,
                              void* d_out, int out_size, void* d_ws, size_t ws_size,
                              hipStream_t stream) {
  const float* x      = (const float*)d_in[0];
  const int* ei       = (const int*)d_in[1];    // int32 from harness
  const int* bat      = (const int*)d_in[2];    // int32 from harness
  const float* w1a = (const float*)d_in[3];  const float* b1a = (const float*)d_in[4];
  const float* g1  = (const float*)d_in[5];  const float* be1 = (const float*)d_in[6];
  const float* w1b = (const float*)d_in[7];  const float* b1b = (const float*)d_in[8];
  const float* w2a = (const float*)d_in[9];  const float* b2a = (const float*)d_in[10];
  const float* g2  = (const float*)d_in[11]; const float* be2 = (const float*)d_in[12];
  const float* w2b = (const float*)d_in[13]; const float* b2b = (const float*)d_in[14];
  const float* w3a = (const float*)d_in[15]; const float* b3a = (const float*)d_in[16];
  const float* g3  = (const float*)d_in[17]; const float* be3 = (const float*)d_in[18];
  const float* w3b = (const float*)d_in[19]; const float* b3b = (const float*)d_in[20];
  const float* wh1 = (const float*)d_in[21]; const float* bh1 = (const float*)d_in[22];
  const float* wh2 = (const float*)d_in[23]; const float* bh2 = (const float*)d_in[24];
  float* out = (float*)d_out;

  const int N = in_sizes[0] / 128;   // 50000
  const int E = in_sizes[1] / 2;     // 800000
  const int G = 512;

  // ---- workspace layout: P = f32 region (z / act), Q = split region ----
  char* ws = (char*)d_ws;
  size_t off = 0;
  auto alloc = [&](size_t bytes) {
    void* p = ws + off;
    off = (off + bytes + 255) & ~(size_t)255;
    return p;
  };
  float* Pf = (float*)alloc((size_t)N * 256 * 4);
  unsigned short* Qhi = (unsigned short*)alloc((size_t)N * 256 * 2);
  unsigned short* Qlo = (unsigned short*)alloc((size_t)N * 256 * 2);
  int* adj     = (int*)alloc((size_t)E * 4);
  int* rowptr  = (int*)alloc((size_t)(N + 1) * 4);
  int* cursor  = (int*)alloc((size_t)N * 4);
  int* deg     = (int*)alloc((size_t)N * 4);
  int* partial = (int*)alloc((size_t)N * 4);
  int* bsum    = (int*)alloc(64 * 4);
  unsigned short* wHi = (unsigned short*)alloc(884736 * 2);
  unsigned short* wLo = (unsigned short*)alloc(884736 * 2);
  float* stats = (float*)alloc(512 * 4);
  float* scsh  = (float*)alloc(512 * 4);
  int* gs      = (int*)alloc(G * 4);
  int* ge      = (int*)alloc(G * 4);
  unsigned short* poolHi = (unsigned short*)alloc((size_t)G * 256 * 2);
  unsigned short* poolLo = (unsigned short*)alloc((size_t)G * 256 * 2);
  unsigned short* thidHi = (unsigned short*)alloc((size_t)G * 512 * 2);
  unsigned short* thidLo = (unsigned short*)alloc((size_t)G * 512 * 2);

  // transposed-weight element offsets
  const int o1a = 0, o1b = 32768, o2a = 98304, o2b = 163840, o3a = 229376, o3b = 294912;
  const int oh1 = 360448, oh2 = 491520;   // ends at 884736

  hipMemsetAsync(deg, 0, (size_t)N * 4, stream);
  hipMemsetAsync(gs, 0, (size_t)G * 4, stream);
  hipMemsetAsync(ge, 0, (size_t)G * 4, stream);

  int eb = (E + 255) / 256;
  int nb1 = (N + 1023) >> 10;   // 49 (<=64 required by k_scan2)
  k_hist<<<eb, 256, 0, stream>>>(ei, deg, E);
  k_scan1<<<nb1, 1024, 0, stream>>>(deg, partial, bsum, N);
  k_scan2<<<1, 64, 0, stream>>>(bsum, nb1);
  k_scan3<<<(N + 255) / 256, 256, 0, stream>>>(deg, partial, bsum, rowptr, cursor, N);
  k_fill<<<eb, 256, 0, stream>>>(ei, cursor, adj, E);

  k_prep<<<128, 256, 0, stream>>>(w1a, wHi + o1a, wLo + o1a, 128, 256);
  k_prep<<<256, 256, 0, stream>>>(w1b, wHi + o1b, wLo + o1b, 256, 256);
  k_prep<<<256, 256, 0, stream>>>(w2a, wHi + o2a, wLo + o2a, 256, 256);
  k_prep<<<256, 256, 0, stream>>>(w2b, wHi + o2b, wLo + o2b, 256, 256);
  k_prep<<<256, 256, 0, stream>>>(w3a, wHi + o3a, wLo + o3a, 256, 256);
  k_prep<<<256, 256, 0, stream>>>(w3b, wHi + o3b, wLo + o3b, 256, 256);
  k_prep<<<512, 256, 0, stream>>>(wh1, wHi + oh1, wLo + oh1, 256, 512);
  k_prep<<<1536, 256, 0, stream>>>(wh2, wHi + oh2, wLo + oh2, 512, 768);

  k_bounds<<<(N + 255) / 256, 256, 0, stream>>>(bat, gs, ge, N);

  int nb4 = (N + 3) / 4;
  int bnb = (N * 32 + 255) / 256;
  const int mb = (N + 127) / 128;        // 391
  const int per = (mb + 7) / 8;          // 49
  dim3 gg(per * 16);                     // XCD-pair swizzled flat grid

  // ---- layer 1 ----
  k_agg<128><<<nb4, 256, 0, stream>>>(x, Qhi, Qlo, rowptr, adj, N);
  hipMemsetAsync(stats, 0, 512 * 4, stream);
  k_gemm<0, true, false, true><<<gg, 256, 0, stream>>>(Qhi, Qlo, N, 128, 256, mb, per, wHi + o1a, wLo + o1a, b1a, Pf, nullptr, nullptr, stats);
  k_finalize<<<1, 256, 0, stream>>>(stats, g1, be1, scsh, N);
  k_bn<<<bnb, 256, 0, stream>>>(Pf, scsh, Qhi, Qlo, N);
  k_gemm<1, false, false, true><<<gg, 256, 0, stream>>>(Qhi, Qlo, N, 256, 256, mb, per, wHi + o1b, wLo + o1b, b1b, Pf, nullptr, nullptr, nullptr);

  // ---- layer 2 ----
  k_agg<256><<<nb4, 256, 0, stream>>>(Pf, Qhi, Qlo, rowptr, adj, N);
  hipMemsetAsync(stats, 0, 512 * 4, stream);
  k_gemm<0, true, false, true><<<gg, 256, 0, stream>>>(Qhi, Qlo, N, 256, 256, mb, per, wHi + o2a, wLo + o2a, b2a, Pf, nullptr, nullptr, stats);
  k_finalize<<<1, 256, 0, stream>>>(stats, g2, be2, scsh, N);
  k_bn<<<bnb, 256, 0, stream>>>(Pf, scsh, Qhi, Qlo, N);
  k_gemm<3, false, false, true><<<gg, 256, 0, stream>>>(Qhi, Qlo, N, 256, 256, mb, per, wHi + o2b, wLo + o2b, b2b, Pf, nullptr, nullptr, nullptr);

  // ---- layer 3 ----
  k_agg<256><<<nb4, 256, 0, stream>>>(Pf, Qhi, Qlo, rowptr, adj, N);
  hipMemsetAsync(stats, 0, 512 * 4, stream);
  k_gemm<0, true, false, true><<<gg, 256, 0, stream>>>(Qhi, Qlo, N, 256, 256, mb, per, wHi + o3a, wLo + o3a, b3a, Pf, nullptr, nullptr, stats);
  k_finalize<<<1, 256, 0, stream>>>(stats, g3, be3, scsh, N);
  k_bn<<<bnb, 256, 0, stream>>>(Pf, scsh, Qhi, Qlo, N);
  k_gemm<2, false, false, true><<<gg, 256, 0, stream>>>(Qhi, Qlo, N, 256, 256, mb, per, wHi + o3b, wLo + o3b, b3b, Pf, nullptr, nullptr, nullptr);

  // ---- pool + MFMA heads ----
  k_pool<<<G, 256, 0, stream>>>(Pf, gs, ge, poolHi, poolLo);
  dim3 gh1(4, 4);   // M=512/128, N=512/128
  k_gemm<1, false, true, false><<<gh1, 256, 0, stream>>>(poolHi, poolLo, G, 256, 512, 0, 0, wHi + oh1, wLo + oh1, bh1, nullptr, thidHi, thidLo, nullptr);
  dim3 gh2(4, 6);   // M=512/128, N=768/128
  k_gemm<0, false, false, false><<<gh2, 256, 0, stream>>>(thidHi, thidLo, G, 512, 768, 0, 0, wHi + oh2, wLo + oh2, bh2, out, nullptr, nullptr, nullptr);
}

// Round 8
// 864.340 us; speedup vs baseline: 1.4197x; 1.0110x over previous
//
#include <hip/hip_runtime.h>

// ---------------------------------------------------------------------------
// GIN GraphEncoder on MI355X.
// All GEMMs: MFMA split-bf16 (hi/lo, 3-product ~f32 accuracy), PRESPLIT
// operands staged global->LDS via global_load_lds(16B), BK=32, DOUBLE-BUFFERED
// 2-phase pipeline (issue next K-tile loads BEFORE computing current; one
// barrier/iter whose implicit vmcnt(0) drain is covered by 48 MFMAs).
// Storage swizzle: 16B k-groups XORed within 32-elem blocks (g' = g^(row&3)),
// so staging global addr is linear and ds_read_b128 applies the same XOR.
// Main GEMMs: XCD-pair block swizzle (both N-halves of an M-tile on one XCD).
// Per layer: agg (CSR gather f32 -> split) -> gemmA (z f32 + fused BN stats)
// -> k_bn (BN folded in, relu -> split) -> gemmB (+epilogue). Pool + 2 heads.
// Integer inputs arrive as int32. CSR scan 3-phase. Launches fused (~27).
// ---------------------------------------------------------------------------

typedef __attribute__((ext_vector_type(8))) short short8;   // 8 bf16 for MFMA
typedef __attribute__((ext_vector_type(4))) float f32x4;
typedef __attribute__((ext_vector_type(4))) unsigned short us4;
typedef __attribute__((ext_vector_type(8))) unsigned short us8;

__device__ __forceinline__ unsigned short f2bf(float f) {
  unsigned int b = __float_as_uint(f);
  unsigned int r = 0x7FFFu + ((b >> 16) & 1u);   // round-to-nearest-even
  return (unsigned short)((b + r) >> 16);
}
__device__ __forceinline__ float bf2f(unsigned short u) {
  return __uint_as_float(((unsigned int)u) << 16);
}

// global->LDS 16B async copy; LDS dest is wave-uniform base (HW adds lane*16)
typedef const __attribute__((address_space(1))) unsigned int* gas1;
typedef __attribute__((address_space(3))) unsigned int* las3;
__device__ __forceinline__ void gload16(const void* g, void* l) {
  __builtin_amdgcn_global_load_lds((gas1)g, (las3)l, 16, 0, 0);
}

// swizzled flat index of element (row, k), row length K:
// 16B groups (8 us) XORed within each 32-elem block: g' = g ^ (row&3)
__device__ __forceinline__ size_t swz4_idx(int row, int k, int K) {
  int g = k >> 3;
  return (size_t)row * K + ((g >> 2) << 5) + ((((g & 3) ^ (row & 3)) << 3)) + (k & 7);
}

// ---------------- CSR build + graph bounds (fused) ----------------
__global__ void k_histbounds(const int* __restrict__ ei, int* __restrict__ deg, int E,
                             int eb, const int* __restrict__ batch,
                             int* __restrict__ gs, int* __restrict__ ge, int N) {
  int b = blockIdx.x;
  if (b < eb) {
    int e = b * 256 + threadIdx.x;
    if (e < E) atomicAdd(&deg[ei[E + e]], 1);
  } else {
    int i = (b - eb) * 256 + threadIdx.x;
    if (i < N) {
      int bb = batch[i];
      if (i == 0 || batch[i - 1] != bb) gs[bb] = i;
      if (i == N - 1 || batch[i + 1] != bb) ge[bb] = i + 1;
    }
  }
}

// phase 1: per-block (1024 elems) inclusive scan + block sum
__global__ __launch_bounds__(1024) void k_scan1(const int* __restrict__ deg,
                                                int* __restrict__ partial,
                                                int* __restrict__ bsum, int N) {
  __shared__ int sd[1024];
  int tid = threadIdx.x;
  int i = blockIdx.x * 1024 + tid;
  int v = (i < N) ? deg[i] : 0;
  sd[tid] = v;
  __syncthreads();
  for (int off = 1; off < 1024; off <<= 1) {
    int t = (tid >= off) ? sd[tid - off] : 0;
    __syncthreads();
    sd[tid] += t;
    __syncthreads();
  }
  if (i < N) partial[i] = sd[tid];
  if (tid == 1023) bsum[blockIdx.x] = sd[1023];
}

// phase 2: exclusive scan of <=64 block sums in one wave
__global__ void k_scan2(int* __restrict__ bsum, int nb) {
  int l = threadIdx.x;
  int orig = (l < nb) ? bsum[l] : 0;
  int v = orig;
  for (int off = 1; off < 64; off <<= 1) {
    int t = __shfl_up(v, off);
    if (l >= off) v += t;
  }
  if (l < nb) bsum[l] = v - orig;
}

// phase 3: rowptr / cursor
__global__ void k_scan3(const int* __restrict__ deg, const int* __restrict__ partial,
                        const int* __restrict__ bsum, int* __restrict__ rowptr,
                        int* __restrict__ cursor, int N) {
  int i = blockIdx.x * 256 + threadIdx.x;
  if (i >= N) return;
  int incl = partial[i] + bsum[i >> 10];
  rowptr[i + 1] = incl;
  cursor[i] = incl - deg[i];
  if (i == 0) rowptr[0] = 0;
}

__global__ void k_fill(const int* __restrict__ ei, int* __restrict__ cursor,
                       int* __restrict__ adj, int E) {
  int e = blockIdx.x * 256 + threadIdx.x;
  if (e >= E) return;
  int s = ei[e];
  int d = ei[E + e];
  int pos = atomicAdd(&cursor[d], 1);
  adj[pos] = s;
}

// ---- ALL weights: transpose + split + swizzle in ONE kernel ----
// segments (elem ranges; out offset == range start in wHi/wLo)
__global__ void k_prep_all(const float* __restrict__ w1a, const float* __restrict__ w1b,
                           const float* __restrict__ w2a, const float* __restrict__ w2b,
                           const float* __restrict__ w3a, const float* __restrict__ w3b,
                           const float* __restrict__ wh1, const float* __restrict__ wh2,
                           unsigned short* __restrict__ Hi, unsigned short* __restrict__ Lo) {
  int idx = blockIdx.x * 256 + threadIdx.x;   // [0, 884736)
  const float* W; int K, Nout, lo_;
  if (idx < 32768)       { W = w1a; K = 128; Nout = 256; lo_ = 0; }
  else if (idx < 98304)  { W = w1b; K = 256; Nout = 256; lo_ = 32768; }
  else if (idx < 163840) { W = w2a; K = 256; Nout = 256; lo_ = 98304; }
  else if (idx < 229376) { W = w2b; K = 256; Nout = 256; lo_ = 163840; }
  else if (idx < 294912) { W = w3a; K = 256; Nout = 256; lo_ = 229376; }
  else if (idx < 360448) { W = w3b; K = 256; Nout = 256; lo_ = 294912; }
  else if (idx < 491520) { W = wh1; K = 256; Nout = 512; lo_ = 360448; }
  else                   { W = wh2; K = 512; Nout = 768; lo_ = 491520; }
  int li = idx - lo_;
  int n = li % Nout, k = li / Nout;
  float w = W[k * Nout + n];
  unsigned short h = f2bf(w);
  size_t oi = (size_t)lo_ + swz4_idx(n, k, K);
  Hi[oi] = h;
  Lo[oi] = f2bf(w - bf2f(h));
}

// -------- aggregation: h = X[i] + sum X[adj[e]]; write split+swizzled --------
template <int C>
__global__ __launch_bounds__(256) void k_agg(const float* __restrict__ X,
                                             unsigned short* __restrict__ HHi,
                                             unsigned short* __restrict__ HLo,
                                             const int* __restrict__ rowptr,
                                             const int* __restrict__ adj, int N) {
  int node = blockIdx.x * 4 + (threadIdx.x >> 6);
  if (node >= N) return;
  int lane = threadIdx.x & 63;
  int e0 = rowptr[node], e1 = rowptr[node + 1];
  if constexpr (C == 256) {
    float4 acc = ((const float4*)(X + (size_t)node * C))[lane];
    int e = e0;
    for (; e + 4 <= e1; e += 4) {
      int s0 = adj[e], s1 = adj[e + 1], s2 = adj[e + 2], s3 = adj[e + 3];
      float4 v0 = ((const float4*)(X + (size_t)s0 * C))[lane];
      float4 v1 = ((const float4*)(X + (size_t)s1 * C))[lane];
      float4 v2 = ((const float4*)(X + (size_t)s2 * C))[lane];
      float4 v3 = ((const float4*)(X + (size_t)s3 * C))[lane];
      acc.x += (v0.x + v1.x) + (v2.x + v3.x);
      acc.y += (v0.y + v1.y) + (v2.y + v3.y);
      acc.z += (v0.z + v1.z) + (v2.z + v3.z);
      acc.w += (v0.w + v1.w) + (v2.w + v3.w);
    }
    for (; e < e1; ++e) {
      int s = adj[e];
      float4 v = ((const float4*)(X + (size_t)s * C))[lane];
      acc.x += v.x; acc.y += v.y; acc.z += v.z; acc.w += v.w;
    }
    float vv[4] = {acc.x, acc.y, acc.z, acc.w};
    us4 hv, lv;
#pragma unroll
    for (int j = 0; j < 4; ++j) {
      unsigned short h = f2bf(vv[j]);
      hv[j] = h;
      lv[j] = f2bf(vv[j] - bf2f(h));
    }
    size_t oi = (size_t)node * 256 + ((lane >> 3) << 5) +
                ((((lane >> 1) & 3) ^ (node & 3)) << 3) + ((lane & 1) << 2);
    *(us4*)(HHi + oi) = hv;
    *(us4*)(HLo + oi) = lv;
  } else {  // C == 128
    float2 acc = ((const float2*)(X + (size_t)node * C))[lane];
    int e = e0;
    for (; e + 4 <= e1; e += 4) {
      int s0 = adj[e], s1 = adj[e + 1], s2 = adj[e + 2], s3 = adj[e + 3];
      float2 v0 = ((const float2*)(X + (size_t)s0 * C))[lane];
      float2 v1 = ((const float2*)(X + (size_t)s1 * C))[lane];
      float2 v2 = ((const float2*)(X + (size_t)s2 * C))[lane];
      float2 v3 = ((const float2*)(X + (size_t)s3 * C))[lane];
      acc.x += (v0.x + v1.x) + (v2.x + v3.x);
      acc.y += (v0.y + v1.y) + (v2.y + v3.y);
    }
    for (; e < e1; ++e) {
      int s = adj[e];
      float2 v = ((const float2*)(X + (size_t)s * C))[lane];
      acc.x += v.x; acc.y += v.y;
    }
    unsigned short hx = f2bf(acc.x), hy = f2bf(acc.y);
    ushort2 hv = {hx, hy};
    ushort2 lv = {f2bf(acc.x - bf2f(hx)), f2bf(acc.y - bf2f(hy))};
    size_t oi = (size_t)node * 128 + ((lane >> 4) << 5) +
                ((((lane >> 2) & 3) ^ (node & 3)) << 3) + ((lane & 3) << 1);
    *(ushort2*)(HHi + oi) = hv;
    *(ushort2*)(HLo + oi) = lv;
  }
}

// -------- BN+relu elementwise (finalize folded in): z f32 -> split bf16 -----
// Recomputes sc/sh from stats with the exact op order of the old k_finalize
// (bit-identical results), removing a launch + the scsh round-trip.
__global__ __launch_bounds__(256) void k_bn(const float* __restrict__ Z,
                                            const float* __restrict__ stats,
                                            const float* __restrict__ g,
                                            const float* __restrict__ be,
                                            unsigned short* __restrict__ OHi,
                                            unsigned short* __restrict__ OLo,
                                            int N) {
  int t = blockIdx.x * 256 + threadIdx.x;    // one 8-elem group per thread
  if (t >= N * 32) return;
  int row = t >> 5, gg_ = t & 31;
  int k0 = gg_ << 3;
  const float* zp = Z + (size_t)row * 256 + k0;
  float4 v0 = *(const float4*)zp;
  float4 v1 = *(const float4*)(zp + 4);
  float f[8] = {v0.x, v0.y, v0.z, v0.w, v1.x, v1.y, v1.z, v1.w};
  us8 hv, lv;
#pragma unroll
  for (int j = 0; j < 8; ++j) {
    int kc = k0 + j;
    float mu = stats[kc] / (float)N;
    float var = stats[256 + kc] / (float)N - mu * mu;
    float sc = g[kc] * rsqrtf(var + 1e-5f);
    float sh = be[kc] - mu * sc;
    float o = fmaxf(f[j] * sc + sh, 0.f);
    unsigned short h = f2bf(o);
    hv[j] = h;
    lv[j] = f2bf(o - bf2f(h));
  }
  size_t oi = (size_t)row * 256 + ((gg_ >> 2) << 5) + (((gg_ & 3) ^ (row & 3)) << 3);
  *(us8*)(OHi + oi) = hv;
  *(us8*)(OLo + oi) = lv;
}

// ------------ MFMA GEMM: 2-phase double-buffered (BK=32, 64KB LDS) ----------
// Out[M][Nld] = A[M][K] @ Wt^T + bias, A/W presplit+swizzled.
// Pipeline: stage(buf0) -> barrier -> { stage(buf^1, t+1); compute(buf);
// barrier } -> compute(last). The barrier's implicit vmcnt(0) drain lands
// after 48 MFMAs of cover instead of immediately after the loads.
// EPI: 0 none, 1 relu, 2 tanh, 3 relu(tanh). STATS: fused BN sum/sumsq.
// OSPLIT: write split+swizzled (relu). XSWZ: XCD-pair block swizzle.
template <int EPI, bool STATS, bool OSPLIT, bool XSWZ>
__global__ __launch_bounds__(256) void k_gemm(
    const unsigned short* __restrict__ AHi, const unsigned short* __restrict__ ALo,
    int M, int K, int Nld, int mb, int per,
    const unsigned short* __restrict__ WHi, const unsigned short* __restrict__ WLo,
    const float* __restrict__ bias, float* __restrict__ Out,
    unsigned short* __restrict__ OHi, unsigned short* __restrict__ OLo,
    float* __restrict__ stats) {
  __shared__ unsigned short aHi[2][4096], aLo[2][4096], bHi[2][4096], bLo[2][4096];
  int bx, by;
  if constexpr (XSWZ) {
    int xcd = blockIdx.x & 7, slot = blockIdx.x >> 3;
    bx = xcd * per + (slot >> 1);
    by = slot & 1;
    if (bx >= mb) return;
  } else {
    bx = blockIdx.x;
    by = blockIdx.y;
  }
  const int tid = threadIdx.x;
  const int lane = tid & 63, w = tid >> 6;
  const int wm = w >> 1, wn = w & 1;
  const int m0 = bx * 128, n0 = by * 128;

  f32x4 zero = {0.f, 0.f, 0.f, 0.f};
  f32x4 acc[4][4];
#pragma unroll
  for (int i = 0; i < 4; ++i)
#pragma unroll
    for (int j = 0; j < 4; ++j) acc[i][j] = zero;

  // staging: wave w rows [32w,32w+32); issue q: rows 32w+16q+(lane>>2),
  // slot lane&3; LDS linear (lane*16 off wave-uniform base).
  const int rq = lane >> 2;
  const int k8s = lane & 3;

  auto stage = [&](int buf, int kb) {
#pragma unroll
    for (int q = 0; q < 2; ++q) {
      int rloc = (w << 5) + (q << 4) + rq;
      int ra = m0 + rloc; if (ra >= M) ra = M - 1;   // clamp tail (junk never stored)
      size_t ga = (size_t)ra * K + kb + k8s * 8;     // swizzles cancel -> linear
      size_t gb = (size_t)(n0 + rloc) * K + kb + k8s * 8;
      unsigned bo = (w << 11) + (q << 10);           // wave-uniform LDS base
      gload16(AHi + ga, (char*)&aHi[buf][0] + bo);
      gload16(ALo + ga, (char*)&aLo[buf][0] + bo);
      gload16(WHi + gb, (char*)&bHi[buf][0] + bo);
      gload16(WLo + gb, (char*)&bLo[buf][0] + bo);
    }
  };
  auto compute = [&](int buf) {
    const int j = lane >> 4;
    short8 bh[4], bl[4];
#pragma unroll
    for (int ni = 0; ni < 4; ++ni) {
      int r = wn * 64 + ni * 16 + (lane & 15);
      int bo = r * 64 + ((j ^ (r & 3)) << 4);
      bh[ni] = *(const short8*)((const char*)&bHi[buf][0] + bo);
      bl[ni] = *(const short8*)((const char*)&bLo[buf][0] + bo);
    }
#pragma unroll
    for (int mi = 0; mi < 4; ++mi) {
      int r = wm * 64 + mi * 16 + (lane & 15);
      int bo = r * 64 + ((j ^ (r & 3)) << 4);
      short8 ah = *(const short8*)((const char*)&aHi[buf][0] + bo);
      short8 al = *(const short8*)((const char*)&aLo[buf][0] + bo);
#pragma unroll
      for (int ni = 0; ni < 4; ++ni) {
        acc[mi][ni] = __builtin_amdgcn_mfma_f32_16x16x32_bf16(ah, bh[ni], acc[mi][ni], 0, 0, 0);
        acc[mi][ni] = __builtin_amdgcn_mfma_f32_16x16x32_bf16(ah, bl[ni], acc[mi][ni], 0, 0, 0);
        acc[mi][ni] = __builtin_amdgcn_mfma_f32_16x16x32_bf16(al, bh[ni], acc[mi][ni], 0, 0, 0);
      }
    }
  };

  stage(0, 0);
  __syncthreads();                 // drain prologue loads
  int cur = 0;
  for (int kb = 32; kb < K; kb += 32) {
    stage(cur ^ 1, kb);            // async loads into free buffer
    compute(cur);                  // 48 MFMAs cover the load latency
    __syncthreads();               // drain this wave's loads + release buffer
    cur ^= 1;
  }
  compute(cur);                    // last tile, no prefetch

  // epilogue: C/D layout col = lane&15, row = (lane>>4)*4 + r   [m89-verified]
#pragma unroll
  for (int ni = 0; ni < 4; ++ni) {
    int col = n0 + wn * 64 + ni * 16 + (lane & 15);
    float bc = bias[col];
    float s = 0.f, q = 0.f;
#pragma unroll
    for (int mi = 0; mi < 4; ++mi) {
      int rbase = m0 + wm * 64 + mi * 16 + (lane >> 4) * 4;
#pragma unroll
      for (int r = 0; r < 4; ++r) {
        int row = rbase + r;
        if (row < M) {
          float o = acc[mi][ni][r] + bc;
          if (STATS) { s += o; q += o * o; }
          if (OSPLIT) {
            o = fmaxf(o, 0.f);   // relu (head1)
            unsigned short h = f2bf(o);
            size_t oi = swz4_idx(row, col, Nld);
            OHi[oi] = h;
            OLo[oi] = f2bf(o - bf2f(h));
          } else {
            if (EPI == 1) o = fmaxf(o, 0.f);
            else if (EPI == 2) o = tanhf(o);
            else if (EPI == 3) o = fmaxf(tanhf(o), 0.f);
            Out[(size_t)row * Nld + col] = o;
          }
        }
      }
    }
    if (STATS) {
      s += __shfl_xor(s, 16); s += __shfl_xor(s, 32);
      q += __shfl_xor(q, 16); q += __shfl_xor(q, 32);
      if ((lane >> 4) == 0) {
        atomicAdd(&stats[col], s);
        atomicAdd(&stats[256 + col], q);
      }
    }
  }
}

// ---------------- pooling ----------------
// 4 waves stride rows, float4 lanes, LDS reduce; write split+swizzled.
__global__ __launch_bounds__(256) void k_pool(const float* __restrict__ Hf,
                                              const int* __restrict__ gs,
                                              const int* __restrict__ ge,
                                              unsigned short* __restrict__ PHi,
                                              unsigned short* __restrict__ PLo) {
  __shared__ float4 red[4][64];
  int gi = blockIdx.x;
  int s = gs[gi], e = ge[gi];
  int w = threadIdx.x >> 6, lane = threadIdx.x & 63;
  float4 acc = {0.f, 0.f, 0.f, 0.f};
  for (int r = s + w; r < e; r += 4) {
    float4 v = ((const float4*)(Hf + (size_t)r * 256))[lane];
    acc.x += v.x; acc.y += v.y; acc.z += v.z; acc.w += v.w;
  }
  red[w][lane] = acc;
  __syncthreads();
  if (w == 0) {
    float4 a = red[0][lane], b = red[1][lane], c = red[2][lane], d = red[3][lane];
    float inv = 1.0f / fmaxf((float)(e - s), 1.0f);
    float vv[4] = {(a.x + b.x + c.x + d.x) * inv, (a.y + b.y + c.y + d.y) * inv,
                   (a.z + b.z + c.z + d.z) * inv, (a.w + b.w + c.w + d.w) * inv};
    us4 hv, lv;
#pragma unroll
    for (int j = 0; j < 4; ++j) {
      unsigned short h = f2bf(vv[j]);
      hv[j] = h;
      lv[j] = f2bf(vv[j] - bf2f(h));
    }
    size_t oi = (size_t)gi * 256 + ((lane >> 3) << 5) +
                ((((lane >> 1) & 3) ^ (gi & 3)) << 3) + ((lane & 1) << 2);
    *(us4*)(PHi + oi) = hv;
    *(us4*)(PLo + oi) = lv;
  }
}

// ---------------------------------------------------------------------------
extern "C" void kernel_launch(void* const* d_in, const int* in_sizes, int n_in,
                              void* d_out, int out_size, void* d_ws, size_t ws_size,
                              hipStream_t stream) {
  const float* x      = (const float*)d_in[0];
  const int* ei       = (const int*)d_in[1];    // int32 from harness
  const int* bat      = (const int*)d_in[2];    // int32 from harness
  const float* w1a = (const float*)d_in[3];  const float* b1a = (const float*)d_in[4];
  const float* g1  = (const float*)d_in[5];  const float* be1 = (const float*)d_in[6];
  const float* w1b = (const float*)d_in[7];  const float* b1b = (const float*)d_in[8];
  const float* w2a = (const float*)d_in[9];  const float* b2a = (const float*)d_in[10];
  const float* g2  = (const float*)d_in[11]; const float* be2 = (const float*)d_in[12];
  const float* w2b = (const float*)d_in[13]; const float* b2b = (const float*)d_in[14];
  const float* w3a = (const float*)d_in[15]; const float* b3a = (const float*)d_in[16];
  const float* g3  = (const float*)d_in[17]; const float* be3 = (const float*)d_in[18];
  const float* w3b = (const float*)d_in[19]; const float* b3b = (const float*)d_in[20];
  const float* wh1 = (const float*)d_in[21]; const float* bh1 = (const float*)d_in[22];
  const float* wh2 = (const float*)d_in[23]; const float* bh2 = (const float*)d_in[24];
  float* out = (float*)d_out;

  const int N = in_sizes[0] / 128;   // 50000
  const int E = in_sizes[1] / 2;     // 800000
  const int G = 512;

  // ---- workspace layout: P = f32 region (z / act), Q = split region ----
  char* ws = (char*)d_ws;
  size_t off = 0;
  auto alloc = [&](size_t bytes) {
    void* p = ws + off;
    off = (off + bytes + 255) & ~(size_t)255;
    return p;
  };
  float* Pf = (float*)alloc((size_t)N * 256 * 4);
  unsigned short* Qhi = (unsigned short*)alloc((size_t)N * 256 * 2);
  unsigned short* Qlo = (unsigned short*)alloc((size_t)N * 256 * 2);
  int* adj     = (int*)alloc((size_t)E * 4);
  int* rowptr  = (int*)alloc((size_t)(N + 1) * 4);
  int* cursor  = (int*)alloc((size_t)N * 4);
  int* deg     = (int*)alloc((size_t)N * 4);
  int* partial = (int*)alloc((size_t)N * 4);
  int* bsum    = (int*)alloc(64 * 4);
  unsigned short* wHi = (unsigned short*)alloc(884736 * 2);
  unsigned short* wLo = (unsigned short*)alloc(884736 * 2);
  float* stats = (float*)alloc(512 * 4);
  int* gs      = (int*)alloc(G * 4);
  int* ge      = (int*)alloc(G * 4);
  unsigned short* poolHi = (unsigned short*)alloc((size_t)G * 256 * 2);
  unsigned short* poolLo = (unsigned short*)alloc((size_t)G * 256 * 2);
  unsigned short* thidHi = (unsigned short*)alloc((size_t)G * 512 * 2);
  unsigned short* thidLo = (unsigned short*)alloc((size_t)G * 512 * 2);

  // transposed-weight element offsets (match k_prep_all segment table)
  const int o1a = 0, o1b = 32768, o2a = 98304, o2b = 163840, o3a = 229376, o3b = 294912;
  const int oh1 = 360448, oh2 = 491520;   // ends at 884736

  hipMemsetAsync(deg, 0, (size_t)N * 4, stream);
  hipMemsetAsync(gs, 0, (size_t)G * 4, stream);
  hipMemsetAsync(ge, 0, (size_t)G * 4, stream);

  int eb = (E + 255) / 256;
  int nbN = (N + 255) / 256;
  int nb1 = (N + 1023) >> 10;   // 49 (<=64 required by k_scan2)
  k_histbounds<<<eb + nbN, 256, 0, stream>>>(ei, deg, E, eb, bat, gs, ge, N);
  k_scan1<<<nb1, 1024, 0, stream>>>(deg, partial, bsum, N);
  k_scan2<<<1, 64, 0, stream>>>(bsum, nb1);
  k_scan3<<<nbN, 256, 0, stream>>>(deg, partial, bsum, rowptr, cursor, N);
  k_fill<<<eb, 256, 0, stream>>>(ei, cursor, adj, E);

  k_prep_all<<<3456, 256, 0, stream>>>(w1a, w1b, w2a, w2b, w3a, w3b, wh1, wh2, wHi, wLo);

  int nb4 = (N + 3) / 4;
  int bnb = (N * 32 + 255) / 256;
  const int mb = (N + 127) / 128;        // 391
  const int per = (mb + 7) / 8;          // 49
  dim3 gg(per * 16);                     // XCD-pair swizzled flat grid

  // ---- layer 1 ----
  k_agg<128><<<nb4, 256, 0, stream>>>(x, Qhi, Qlo, rowptr, adj, N);
  hipMemsetAsync(stats, 0, 512 * 4, stream);
  k_gemm<0, true, false, true><<<gg, 256, 0, stream>>>(Qhi, Qlo, N, 128, 256, mb, per, wHi + o1a, wLo + o1a, b1a, Pf, nullptr, nullptr, stats);
  k_bn<<<bnb, 256, 0, stream>>>(Pf, stats, g1, be1, Qhi, Qlo, N);
  k_gemm<1, false, false, true><<<gg, 256, 0, stream>>>(Qhi, Qlo, N, 256, 256, mb, per, wHi + o1b, wLo + o1b, b1b, Pf, nullptr, nullptr, nullptr);

  // ---- layer 2 ----
  k_agg<256><<<nb4, 256, 0, stream>>>(Pf, Qhi, Qlo, rowptr, adj, N);
  hipMemsetAsync(stats, 0, 512 * 4, stream);
  k_gemm<0, true, false, true><<<gg, 256, 0, stream>>>(Qhi, Qlo, N, 256, 256, mb, per, wHi + o2a, wLo + o2a, b2a, Pf, nullptr, nullptr, stats);
  k_bn<<<bnb, 256, 0, stream>>>(Pf, stats, g2, be2, Qhi, Qlo, N);
  k_gemm<3, false, false, true><<<gg, 256, 0, stream>>>(Qhi, Qlo, N, 256, 256, mb, per, wHi + o2b, wLo + o2b, b2b, Pf, nullptr, nullptr, nullptr);

  // ---- layer 3 ----
  k_agg<256><<<nb4, 256, 0, stream>>>(Pf, Qhi, Qlo, rowptr, adj, N);
  hipMemsetAsync(stats, 0, 512 * 4, stream);
  k_gemm<0, true, false, true><<<gg, 256, 0, stream>>>(Qhi, Qlo, N, 256, 256, mb, per, wHi + o3a, wLo + o3a, b3a, Pf, nullptr, nullptr, stats);
  k_bn<<<bnb, 256, 0, stream>>>(Pf, stats, g3, be3, Qhi, Qlo, N);
  k_gemm<2, false, false, true><<<gg, 256, 0, stream>>>(Qhi, Qlo, N, 256, 256, mb, per, wHi + o3b, wLo + o3b, b3b, Pf, nullptr, nullptr, nullptr);

  // ---- pool + MFMA heads ----
  k_pool<<<G, 256, 0, stream>>>(Pf, gs, ge, poolHi, poolLo);
  dim3 gh1(4, 4);   // M=512/128, N=512/128
  k_gemm<1, false, true, false><<<gh1, 256, 0, stream>>>(poolHi, poolLo, G, 256, 512, 0, 0, wHi + oh1, wLo + oh1, bh1, nullptr, thidHi, thidLo, nullptr);
  dim3 gh2(4, 6);   // M=512/128, N=768/128
  k_gemm<0, false, false, false><<<gh2, 256, 0, stream>>>(thidHi, thidLo, G, 512, 768, 0, 0, wHi + oh2, wLo + oh2, bh2, out, nullptr, nullptr, nullptr);
}

// Round 9
// 852.165 us; speedup vs baseline: 1.4400x; 1.0143x over previous
//
#include <hip/hip_runtime.h>

// ---------------------------------------------------------------------------
// GIN GraphEncoder on MI355X.
// All GEMMs: MFMA split-bf16 (hi/lo, 3-product ~f32 accuracy), PRESPLIT
// operands staged global->LDS via global_load_lds(16B), BK=32, single-buffer
// 32KB LDS (m97 regime, 4-5 blocks/CU).
// Storage swizzle (R9): 16B k-groups XORed within 32-elem blocks with
// sw(row) = (row&3)^((row>>2)&3) -- spreads ds_read_b128 fragment reads
// evenly over all 32 banks (old (row&3)-only form left 4-8-way conflicts
// because LDS rows are 64B and bank space is 128B). Staging global addr is
// linear (swizzles cancel); ds_read applies the same XOR.
// Main GEMMs: XCD-pair block swizzle (both N-halves of an M-tile on one XCD).
// Per layer: agg (CSR gather f32 -> split) -> gemmA (z f32 + fused BN stats)
// -> k_bn (BN folded in, relu -> split) -> gemmB (+epilogue). Pool + 2 heads.
// Integer inputs arrive as int32. CSR scan 3-phase. Launches fused (~27).
// ---------------------------------------------------------------------------

typedef __attribute__((ext_vector_type(8))) short short8;   // 8 bf16 for MFMA
typedef __attribute__((ext_vector_type(4))) float f32x4;
typedef __attribute__((ext_vector_type(4))) unsigned short us4;
typedef __attribute__((ext_vector_type(8))) unsigned short us8;

__device__ __forceinline__ unsigned short f2bf(float f) {
  unsigned int b = __float_as_uint(f);
  unsigned int r = 0x7FFFu + ((b >> 16) & 1u);   // round-to-nearest-even
  return (unsigned short)((b + r) >> 16);
}
__device__ __forceinline__ float bf2f(unsigned short u) {
  return __uint_as_float(((unsigned int)u) << 16);
}

// bank-spread row swizzle value (4-group domain)
__device__ __forceinline__ int swv(int row) {
  return (row & 3) ^ ((row >> 2) & 3);
}

// global->LDS 16B async copy; LDS dest is wave-uniform base (HW adds lane*16)
typedef const __attribute__((address_space(1))) unsigned int* gas1;
typedef __attribute__((address_space(3))) unsigned int* las3;
__device__ __forceinline__ void gload16(const void* g, void* l) {
  __builtin_amdgcn_global_load_lds((gas1)g, (las3)l, 16, 0, 0);
}

// swizzled flat index of element (row, k), row length K:
// 16B groups (8 us) XORed within each 32-elem block: g' = g ^ swv(row)
__device__ __forceinline__ size_t swz4_idx(int row, int k, int K) {
  int g = k >> 3;
  return (size_t)row * K + ((g >> 2) << 5) + ((((g & 3) ^ swv(row)) << 3)) + (k & 7);
}

// ---------------- CSR build + graph bounds (fused) ----------------
__global__ void k_histbounds(const int* __restrict__ ei, int* __restrict__ deg, int E,
                             int eb, const int* __restrict__ batch,
                             int* __restrict__ gs, int* __restrict__ ge, int N) {
  int b = blockIdx.x;
  if (b < eb) {
    int e = b * 256 + threadIdx.x;
    if (e < E) atomicAdd(&deg[ei[E + e]], 1);
  } else {
    int i = (b - eb) * 256 + threadIdx.x;
    if (i < N) {
      int bb = batch[i];
      if (i == 0 || batch[i - 1] != bb) gs[bb] = i;
      if (i == N - 1 || batch[i + 1] != bb) ge[bb] = i + 1;
    }
  }
}

// phase 1: per-block (1024 elems) inclusive scan + block sum
__global__ __launch_bounds__(1024) void k_scan1(const int* __restrict__ deg,
                                                int* __restrict__ partial,
                                                int* __restrict__ bsum, int N) {
  __shared__ int sd[1024];
  int tid = threadIdx.x;
  int i = blockIdx.x * 1024 + tid;
  int v = (i < N) ? deg[i] : 0;
  sd[tid] = v;
  __syncthreads();
  for (int off = 1; off < 1024; off <<= 1) {
    int t = (tid >= off) ? sd[tid - off] : 0;
    __syncthreads();
    sd[tid] += t;
    __syncthreads();
  }
  if (i < N) partial[i] = sd[tid];
  if (tid == 1023) bsum[blockIdx.x] = sd[1023];
}

// phase 2: exclusive scan of <=64 block sums in one wave
__global__ void k_scan2(int* __restrict__ bsum, int nb) {
  int l = threadIdx.x;
  int orig = (l < nb) ? bsum[l] : 0;
  int v = orig;
  for (int off = 1; off < 64; off <<= 1) {
    int t = __shfl_up(v, off);
    if (l >= off) v += t;
  }
  if (l < nb) bsum[l] = v - orig;
}

// phase 3: rowptr / cursor
__global__ void k_scan3(const int* __restrict__ deg, const int* __restrict__ partial,
                        const int* __restrict__ bsum, int* __restrict__ rowptr,
                        int* __restrict__ cursor, int N) {
  int i = blockIdx.x * 256 + threadIdx.x;
  if (i >= N) return;
  int incl = partial[i] + bsum[i >> 10];
  rowptr[i + 1] = incl;
  cursor[i] = incl - deg[i];
  if (i == 0) rowptr[0] = 0;
}

__global__ void k_fill(const int* __restrict__ ei, int* __restrict__ cursor,
                       int* __restrict__ adj, int E) {
  int e = blockIdx.x * 256 + threadIdx.x;
  if (e >= E) return;
  int s = ei[e];
  int d = ei[E + e];
  int pos = atomicAdd(&cursor[d], 1);
  adj[pos] = s;
}

// ---- ALL weights: transpose + split + swizzle in ONE kernel ----
__global__ void k_prep_all(const float* __restrict__ w1a, const float* __restrict__ w1b,
                           const float* __restrict__ w2a, const float* __restrict__ w2b,
                           const float* __restrict__ w3a, const float* __restrict__ w3b,
                           const float* __restrict__ wh1, const float* __restrict__ wh2,
                           unsigned short* __restrict__ Hi, unsigned short* __restrict__ Lo) {
  int idx = blockIdx.x * 256 + threadIdx.x;   // [0, 884736)
  const float* W; int K, Nout, lo_;
  if (idx < 32768)       { W = w1a; K = 128; Nout = 256; lo_ = 0; }
  else if (idx < 98304)  { W = w1b; K = 256; Nout = 256; lo_ = 32768; }
  else if (idx < 163840) { W = w2a; K = 256; Nout = 256; lo_ = 98304; }
  else if (idx < 229376) { W = w2b; K = 256; Nout = 256; lo_ = 163840; }
  else if (idx < 294912) { W = w3a; K = 256; Nout = 256; lo_ = 229376; }
  else if (idx < 360448) { W = w3b; K = 256; Nout = 256; lo_ = 294912; }
  else if (idx < 491520) { W = wh1; K = 256; Nout = 512; lo_ = 360448; }
  else                   { W = wh2; K = 512; Nout = 768; lo_ = 491520; }
  int li = idx - lo_;
  int n = li % Nout, k = li / Nout;
  float w = W[k * Nout + n];
  unsigned short h = f2bf(w);
  size_t oi = (size_t)lo_ + swz4_idx(n, k, K);
  Hi[oi] = h;
  Lo[oi] = f2bf(w - bf2f(h));
}

// -------- aggregation: h = X[i] + sum X[adj[e]]; write split+swizzled --------
template <int C>
__global__ __launch_bounds__(256) void k_agg(const float* __restrict__ X,
                                             unsigned short* __restrict__ HHi,
                                             unsigned short* __restrict__ HLo,
                                             const int* __restrict__ rowptr,
                                             const int* __restrict__ adj, int N) {
  int node = blockIdx.x * 4 + (threadIdx.x >> 6);
  if (node >= N) return;
  int lane = threadIdx.x & 63;
  int e0 = rowptr[node], e1 = rowptr[node + 1];
  if constexpr (C == 256) {
    float4 acc = ((const float4*)(X + (size_t)node * C))[lane];
    int e = e0;
    for (; e + 4 <= e1; e += 4) {
      int s0 = adj[e], s1 = adj[e + 1], s2 = adj[e + 2], s3 = adj[e + 3];
      float4 v0 = ((const float4*)(X + (size_t)s0 * C))[lane];
      float4 v1 = ((const float4*)(X + (size_t)s1 * C))[lane];
      float4 v2 = ((const float4*)(X + (size_t)s2 * C))[lane];
      float4 v3 = ((const float4*)(X + (size_t)s3 * C))[lane];
      acc.x += (v0.x + v1.x) + (v2.x + v3.x);
      acc.y += (v0.y + v1.y) + (v2.y + v3.y);
      acc.z += (v0.z + v1.z) + (v2.z + v3.z);
      acc.w += (v0.w + v1.w) + (v2.w + v3.w);
    }
    for (; e < e1; ++e) {
      int s = adj[e];
      float4 v = ((const float4*)(X + (size_t)s * C))[lane];
      acc.x += v.x; acc.y += v.y; acc.z += v.z; acc.w += v.w;
    }
    float vv[4] = {acc.x, acc.y, acc.z, acc.w};
    us4 hv, lv;
#pragma unroll
    for (int j = 0; j < 4; ++j) {
      unsigned short h = f2bf(vv[j]);
      hv[j] = h;
      lv[j] = f2bf(vv[j] - bf2f(h));
    }
    // lane covers cols lane*4..+3 -> group g = lane>>1, half = lane&1
    size_t oi = (size_t)node * 256 + ((lane >> 3) << 5) +
                ((((lane >> 1) & 3) ^ swv(node)) << 3) + ((lane & 1) << 2);
    *(us4*)(HHi + oi) = hv;
    *(us4*)(HLo + oi) = lv;
  } else {  // C == 128
    float2 acc = ((const float2*)(X + (size_t)node * C))[lane];
    int e = e0;
    for (; e + 4 <= e1; e += 4) {
      int s0 = adj[e], s1 = adj[e + 1], s2 = adj[e + 2], s3 = adj[e + 3];
      float2 v0 = ((const float2*)(X + (size_t)s0 * C))[lane];
      float2 v1 = ((const float2*)(X + (size_t)s1 * C))[lane];
      float2 v2 = ((const float2*)(X + (size_t)s2 * C))[lane];
      float2 v3 = ((const float2*)(X + (size_t)s3 * C))[lane];
      acc.x += (v0.x + v1.x) + (v2.x + v3.x);
      acc.y += (v0.y + v1.y) + (v2.y + v3.y);
    }
    for (; e < e1; ++e) {
      int s = adj[e];
      float2 v = ((const float2*)(X + (size_t)s * C))[lane];
      acc.x += v.x; acc.y += v.y;
    }
    unsigned short hx = f2bf(acc.x), hy = f2bf(acc.y);
    ushort2 hv = {hx, hy};
    ushort2 lv = {f2bf(acc.x - bf2f(hx)), f2bf(acc.y - bf2f(hy))};
    size_t oi = (size_t)node * 128 + ((lane >> 4) << 5) +
                ((((lane >> 2) & 3) ^ swv(node)) << 3) + ((lane & 3) << 1);
    *(ushort2*)(HHi + oi) = hv;
    *(ushort2*)(HLo + oi) = lv;
  }
}

// -------- BN+relu elementwise (finalize folded in): z f32 -> split bf16 -----
__global__ __launch_bounds__(256) void k_bn(const float* __restrict__ Z,
                                            const float* __restrict__ stats,
                                            const float* __restrict__ g,
                                            const float* __restrict__ be,
                                            unsigned short* __restrict__ OHi,
                                            unsigned short* __restrict__ OLo,
                                            int N) {
  int t = blockIdx.x * 256 + threadIdx.x;    // one 8-elem group per thread
  if (t >= N * 32) return;
  int row = t >> 5, gg_ = t & 31;
  int k0 = gg_ << 3;
  const float* zp = Z + (size_t)row * 256 + k0;
  float4 v0 = *(const float4*)zp;
  float4 v1 = *(const float4*)(zp + 4);
  float f[8] = {v0.x, v0.y, v0.z, v0.w, v1.x, v1.y, v1.z, v1.w};
  us8 hv, lv;
#pragma unroll
  for (int j = 0; j < 8; ++j) {
    int kc = k0 + j;
    float mu = stats[kc] / (float)N;
    float var = stats[256 + kc] / (float)N - mu * mu;
    float sc = g[kc] * rsqrtf(var + 1e-5f);
    float sh = be[kc] - mu * sc;
    float o = fmaxf(f[j] * sc + sh, 0.f);
    unsigned short h = f2bf(o);
    hv[j] = h;
    lv[j] = f2bf(o - bf2f(h));
  }
  size_t oi = (size_t)row * 256 + ((gg_ >> 2) << 5) + (((gg_ & 3) ^ swv(row)) << 3);
  *(us8*)(OHi + oi) = hv;
  *(us8*)(OLo + oi) = lv;
}

// ------------ MFMA GEMM: single-buffer BK=32, 32KB LDS, bank-spread swizzle --
// Out[M][Nld] = A[M][K] @ Wt^T + bias, A/W presplit+swizzled.
// EPI: 0 none, 1 relu, 2 tanh, 3 relu(tanh). STATS: fused BN sum/sumsq.
// OSPLIT: write split+swizzled (relu). XSWZ: XCD-pair block swizzle.
template <int EPI, bool STATS, bool OSPLIT, bool XSWZ>
__global__ __launch_bounds__(256) void k_gemm(
    const unsigned short* __restrict__ AHi, const unsigned short* __restrict__ ALo,
    int M, int K, int Nld, int mb, int per,
    const unsigned short* __restrict__ WHi, const unsigned short* __restrict__ WLo,
    const float* __restrict__ bias, float* __restrict__ Out,
    unsigned short* __restrict__ OHi, unsigned short* __restrict__ OLo,
    float* __restrict__ stats) {
  __shared__ unsigned short aHi[4096], aLo[4096], bHi[4096], bLo[4096];  // 4x8KB
  int bx, by;
  if constexpr (XSWZ) {
    int xcd = blockIdx.x & 7, slot = blockIdx.x >> 3;
    bx = xcd * per + (slot >> 1);
    by = slot & 1;
    if (bx >= mb) return;
  } else {
    bx = blockIdx.x;
    by = blockIdx.y;
  }
  const int tid = threadIdx.x;
  const int lane = tid & 63, w = tid >> 6;
  const int wm = w >> 1, wn = w & 1;
  const int m0 = bx * 128, n0 = by * 128;

  f32x4 zero = {0.f, 0.f, 0.f, 0.f};
  f32x4 acc[4][4];
#pragma unroll
  for (int i = 0; i < 4; ++i)
#pragma unroll
    for (int j = 0; j < 4; ++j) acc[i][j] = zero;

  // staging: wave w rows [32w,32w+32); issue q: rows 32w+16q+(lane>>2),
  // slot lane&3; LDS linear (lane*16 off wave-uniform base).
  const int rq = lane >> 2;
  const int k8s = lane & 3;

  for (int kb = 0; kb < K; kb += 32) {
    __syncthreads();
#pragma unroll
    for (int q = 0; q < 2; ++q) {
      int rloc = (w << 5) + (q << 4) + rq;
      int ra = m0 + rloc; if (ra >= M) ra = M - 1;   // clamp tail (junk never stored)
      size_t ga = (size_t)ra * K + kb + k8s * 8;     // swizzles cancel -> linear
      size_t gb = (size_t)(n0 + rloc) * K + kb + k8s * 8;
      unsigned bo = (w << 11) + (q << 10);           // wave-uniform LDS base
      gload16(AHi + ga, (char*)aHi + bo);
      gload16(ALo + ga, (char*)aLo + bo);
      gload16(WHi + gb, (char*)bHi + bo);
      gload16(WLo + gb, (char*)bLo + bo);
    }
    __syncthreads();   // compiler drains vmcnt(0) before s_barrier -> LDS ready

    const int j = lane >> 4;
    short8 bh[4], bl[4];
#pragma unroll
    for (int ni = 0; ni < 4; ++ni) {
      int r = wn * 64 + ni * 16 + (lane & 15);
      int bo = r * 64 + ((j ^ swv(r)) << 4);
      bh[ni] = *(const short8*)((const char*)bHi + bo);
      bl[ni] = *(const short8*)((const char*)bLo + bo);
    }
#pragma unroll
    for (int mi = 0; mi < 4; ++mi) {
      int r = wm * 64 + mi * 16 + (lane & 15);
      int bo = r * 64 + ((j ^ swv(r)) << 4);
      short8 ah = *(const short8*)((const char*)aHi + bo);
      short8 al = *(const short8*)((const char*)aLo + bo);
#pragma unroll
      for (int ni = 0; ni < 4; ++ni) {
        acc[mi][ni] = __builtin_amdgcn_mfma_f32_16x16x32_bf16(ah, bh[ni], acc[mi][ni], 0, 0, 0);
        acc[mi][ni] = __builtin_amdgcn_mfma_f32_16x16x32_bf16(ah, bl[ni], acc[mi][ni], 0, 0, 0);
        acc[mi][ni] = __builtin_amdgcn_mfma_f32_16x16x32_bf16(al, bh[ni], acc[mi][ni], 0, 0, 0);
      }
    }
  }

  // epilogue: C/D layout col = lane&15, row = (lane>>4)*4 + r   [m89-verified]
#pragma unroll
  for (int ni = 0; ni < 4; ++ni) {
    int col = n0 + wn * 64 + ni * 16 + (lane & 15);
    float bc = bias[col];
    float s = 0.f, q = 0.f;
#pragma unroll
    for (int mi = 0; mi < 4; ++mi) {
      int rbase = m0 + wm * 64 + mi * 16 + (lane >> 4) * 4;
#pragma unroll
      for (int r = 0; r < 4; ++r) {
        int row = rbase + r;
        if (row < M) {
          float o = acc[mi][ni][r] + bc;
          if (STATS) { s += o; q += o * o; }
          if (OSPLIT) {
            o = fmaxf(o, 0.f);   // relu (head1)
            unsigned short h = f2bf(o);
            size_t oi = swz4_idx(row, col, Nld);
            OHi[oi] = h;
            OLo[oi] = f2bf(o - bf2f(h));
          } else {
            if (EPI == 1) o = fmaxf(o, 0.f);
            else if (EPI == 2) o = tanhf(o);
            else if (EPI == 3) o = fmaxf(tanhf(o), 0.f);
            Out[(size_t)row * Nld + col] = o;
          }
        }
      }
    }
    if (STATS) {
      s += __shfl_xor(s, 16); s += __shfl_xor(s, 32);
      q += __shfl_xor(q, 16); q += __shfl_xor(q, 32);
      if ((lane >> 4) == 0) {
        atomicAdd(&stats[col], s);
        atomicAdd(&stats[256 + col], q);
      }
    }
  }
}

// ---------------- pooling ----------------
// 4 waves stride rows, float4 lanes, LDS reduce; write split+swizzled.
__global__ __launch_bounds__(256) void k_pool(const float* __restrict__ Hf,
                                              const int* __restrict__ gs,
                                              const int* __restrict__ ge,
                                              unsigned short* __restrict__ PHi,
                                              unsigned short* __restrict__ PLo) {
  __shared__ float4 red[4][64];
  int gi = blockIdx.x;
  int s = gs[gi], e = ge[gi];
  int w = threadIdx.x >> 6, lane = threadIdx.x & 63;
  float4 acc = {0.f, 0.f, 0.f, 0.f};
  for (int r = s + w; r < e; r += 4) {
    float4 v = ((const float4*)(Hf + (size_t)r * 256))[lane];
    acc.x += v.x; acc.y += v.y; acc.z += v.z; acc.w += v.w;
  }
  red[w][lane] = acc;
  __syncthreads();
  if (w == 0) {
    float4 a = red[0][lane], b = red[1][lane], c = red[2][lane], d = red[3][lane];
    float inv = 1.0f / fmaxf((float)(e - s), 1.0f);
    float vv[4] = {(a.x + b.x + c.x + d.x) * inv, (a.y + b.y + c.y + d.y) * inv,
                   (a.z + b.z + c.z + d.z) * inv, (a.w + b.w + c.w + d.w) * inv};
    us4 hv, lv;
#pragma unroll
    for (int j = 0; j < 4; ++j) {
      unsigned short h = f2bf(vv[j]);
      hv[j] = h;
      lv[j] = f2bf(vv[j] - bf2f(h));
    }
    size_t oi = (size_t)gi * 256 + ((lane >> 3) << 5) +
                ((((lane >> 1) & 3) ^ swv(gi)) << 3) + ((lane & 1) << 2);
    *(us4*)(PHi + oi) = hv;
    *(us4*)(PLo + oi) = lv;
  }
}

// ---------------------------------------------------------------------------
extern "C" void kernel_launch(void* const* d_in, const int* in_sizes, int n_in,
                              void* d_out, int out_size, void* d_ws, size_t ws_size,
                              hipStream_t stream) {
  const float* x      = (const float*)d_in[0];
  const int* ei       = (const int*)d_in[1];    // int32 from harness
  const int* bat      = (const int*)d_in[2];    // int32 from harness
  const float* w1a = (const float*)d_in[3];  const float* b1a = (const float*)d_in[4];
  const float* g1  = (const float*)d_in[5];  const float* be1 = (const float*)d_in[6];
  const float* w1b = (const float*)d_in[7];  const float* b1b = (const float*)d_in[8];
  const float* w2a = (const float*)d_in[9];  const float* b2a = (const float*)d_in[10];
  const float* g2  = (const float*)d_in[11]; const float* be2 = (const float*)d_in[12];
  const float* w2b = (const float*)d_in[13]; const float* b2b = (const float*)d_in[14];
  const float* w3a = (const float*)d_in[15]; const float* b3a = (const float*)d_in[16];
  const float* g3  = (const float*)d_in[17]; const float* be3 = (const float*)d_in[18];
  const float* w3b = (const float*)d_in[19]; const float* b3b = (const float*)d_in[20];
  const float* wh1 = (const float*)d_in[21]; const float* bh1 = (const float*)d_in[22];
  const float* wh2 = (const float*)d_in[23]; const float* bh2 = (const float*)d_in[24];
  float* out = (float*)d_out;

  const int N = in_sizes[0] / 128;   // 50000
  const int E = in_sizes[1] / 2;     // 800000
  const int G = 512;

  // ---- workspace layout: P = f32 region (z / act), Q = split region ----
  char* ws = (char*)d_ws;
  size_t off = 0;
  auto alloc = [&](size_t bytes) {
    void* p = ws + off;
    off = (off + bytes + 255) & ~(size_t)255;
    return p;
  };
  float* Pf = (float*)alloc((size_t)N * 256 * 4);
  unsigned short* Qhi = (unsigned short*)alloc((size_t)N * 256 * 2);
  unsigned short* Qlo = (unsigned short*)alloc((size_t)N * 256 * 2);
  int* adj     = (int*)alloc((size_t)E * 4);
  int* rowptr  = (int*)alloc((size_t)(N + 1) * 4);
  int* cursor  = (int*)alloc((size_t)N * 4);
  int* deg     = (int*)alloc((size_t)N * 4);
  int* partial = (int*)alloc((size_t)N * 4);
  int* bsum    = (int*)alloc(64 * 4);
  unsigned short* wHi = (unsigned short*)alloc(884736 * 2);
  unsigned short* wLo = (unsigned short*)alloc(884736 * 2);
  float* stats = (float*)alloc(512 * 4);
  int* gs      = (int*)alloc(G * 4);
  int* ge      = (int*)alloc(G * 4);
  unsigned short* poolHi = (unsigned short*)alloc((size_t)G * 256 * 2);
  unsigned short* poolLo = (unsigned short*)alloc((size_t)G * 256 * 2);
  unsigned short* thidHi = (unsigned short*)alloc((size_t)G * 512 * 2);
  unsigned short* thidLo = (unsigned short*)alloc((size_t)G * 512 * 2);

  // transposed-weight element offsets (match k_prep_all segment table)
  const int o1a = 0, o1b = 32768, o2a = 98304, o2b = 163840, o3a = 229376, o3b = 294912;
  const int oh1 = 360448, oh2 = 491520;   // ends at 884736

  hipMemsetAsync(deg, 0, (size_t)N * 4, stream);
  hipMemsetAsync(gs, 0, (size_t)G * 4, stream);
  hipMemsetAsync(ge, 0, (size_t)G * 4, stream);

  int eb = (E + 255) / 256;
  int nbN = (N + 255) / 256;
  int nb1 = (N + 1023) >> 10;   // 49 (<=64 required by k_scan2)
  k_histbounds<<<eb + nbN, 256, 0, stream>>>(ei, deg, E, eb, bat, gs, ge, N);
  k_scan1<<<nb1, 1024, 0, stream>>>(deg, partial, bsum, N);
  k_scan2<<<1, 64, 0, stream>>>(bsum, nb1);
  k_scan3<<<nbN, 256, 0, stream>>>(deg, partial, bsum, rowptr, cursor, N);
  k_fill<<<eb, 256, 0, stream>>>(ei, cursor, adj, E);

  k_prep_all<<<3456, 256, 0, stream>>>(w1a, w1b, w2a, w2b, w3a, w3b, wh1, wh2, wHi, wLo);

  int nb4 = (N + 3) / 4;
  int bnb = (N * 32 + 255) / 256;
  const int mb = (N + 127) / 128;        // 391
  const int per = (mb + 7) / 8;          // 49
  dim3 gg(per * 16);                     // XCD-pair swizzled flat grid

  // ---- layer 1 ----
  k_agg<128><<<nb4, 256, 0, stream>>>(x, Qhi, Qlo, rowptr, adj, N);
  hipMemsetAsync(stats, 0, 512 * 4, stream);
  k_gemm<0, true, false, true><<<gg, 256, 0, stream>>>(Qhi, Qlo, N, 128, 256, mb, per, wHi + o1a, wLo + o1a, b1a, Pf, nullptr, nullptr, stats);
  k_bn<<<bnb, 256, 0, stream>>>(Pf, stats, g1, be1, Qhi, Qlo, N);
  k_gemm<1, false, false, true><<<gg, 256, 0, stream>>>(Qhi, Qlo, N, 256, 256, mb, per, wHi + o1b, wLo + o1b, b1b, Pf, nullptr, nullptr, nullptr);

  // ---- layer 2 ----
  k_agg<256><<<nb4, 256, 0, stream>>>(Pf, Qhi, Qlo, rowptr, adj, N);
  hipMemsetAsync(stats, 0, 512 * 4, stream);
  k_gemm<0, true, false, true><<<gg, 256, 0, stream>>>(Qhi, Qlo, N, 256, 256, mb, per, wHi + o2a, wLo + o2a, b2a, Pf, nullptr, nullptr, stats);
  k_bn<<<bnb, 256, 0, stream>>>(Pf, stats, g2, be2, Qhi, Qlo, N);
  k_gemm<3, false, false, true><<<gg, 256, 0, stream>>>(Qhi, Qlo, N, 256, 256, mb, per, wHi + o2b, wLo + o2b, b2b, Pf, nullptr, nullptr, nullptr);

  // ---- layer 3 ----
  k_agg<256><<<nb4, 256, 0, stream>>>(Pf, Qhi, Qlo, rowptr, adj, N);
  hipMemsetAsync(stats, 0, 512 * 4, stream);
  k_gemm<0, true, false, true><<<gg, 256, 0, stream>>>(Qhi, Qlo, N, 256, 256, mb, per, wHi + o3a, wLo + o3a, b3a, Pf, nullptr, nullptr, stats);
  k_bn<<<bnb, 256, 0, stream>>>(Pf, stats, g3, be3, Qhi, Qlo, N);
  k_gemm<2, false, false, true><<<gg, 256, 0, stream>>>(Qhi, Qlo, N, 256, 256, mb, per, wHi + o3b, wLo + o3b, b3b, Pf, nullptr, nullptr, nullptr);

  // ---- pool + MFMA heads ----
  k_pool<<<G, 256, 0, stream>>>(Pf, gs, ge, poolHi, poolLo);
  dim3 gh1(4, 4);   // M=512/128, N=512/128
  k_gemm<1, false, true, false><<<gh1, 256, 0, stream>>>(poolHi, poolLo, G, 256, 512, 0, 0, wHi + oh1, wLo + oh1, bh1, nullptr, thidHi, thidLo, nullptr);
  dim3 gh2(4, 6);   // M=512/128, N=768/128
  k_gemm<0, false, false, false><<<gh2, 256, 0, stream>>>(thidHi, thidLo, G, 512, 768, 0, 0, wHi + oh2, wLo + oh2, bh2, out, nullptr, nullptr, nullptr);
}